// Round 4
// baseline (1019.070 us; speedup 1.0000x reference)
//
#include <hip/hip_runtime.h>
#include <hip/hip_bf16.h>
#include <stdint.h>
#include <math.h>

// SparseMoeBlock: 8 experts, top-2, H=2048, I=1408, T=8192, fp32 in/out.
// R4: faithful m201-style 8-phase GEMMs: block-level C-quadrant phases,
// one half-tile staged per phase, counted s_waitcnt vmcnt(4) (never 0 in
// main loop), builtin s_barrier (no memory clobber), dummy tail stage for
// uniform vmcnt arithmetic, setprio around MFMA clusters.

#define E_ 8
#define H_ 2048
#define I_ 1408
#define T_ 8192
#define NSLOT (T_ * 2)

typedef __bf16 bf16;
typedef bf16 bf16x4 __attribute__((ext_vector_type(4)));
typedef bf16 bf16x8 __attribute__((ext_vector_type(8)));
typedef float f32x4 __attribute__((ext_vector_type(4)));

__device__ inline void gl2lds16(const void* g, void* l) {
  __builtin_amdgcn_global_load_lds(
      (const __attribute__((address_space(1))) unsigned int*)g,
      (__attribute__((address_space(3))) unsigned int*)l, 16, 0, 0);
}
__device__ __forceinline__ void barr_() { __builtin_amdgcn_s_barrier(); }
__device__ __forceinline__ void vm4_() {
  asm volatile("s_waitcnt vmcnt(4)" ::: "memory");
}

// ---------------- fp32 -> bf16 conversion (weights) ----------------
__global__ __launch_bounds__(256) void cvt_k(const float* __restrict__ in,
                                             bf16* __restrict__ out, int n8) {
  int stride = gridDim.x * blockDim.x;
  for (int i = blockIdx.x * blockDim.x + threadIdx.x; i < n8; i += stride) {
    const float4* p = (const float4*)in + (size_t)i * 2;
    float4 a = p[0], b = p[1];
    bf16x8 o;
    o[0] = (bf16)a.x; o[1] = (bf16)a.y; o[2] = (bf16)a.z; o[3] = (bf16)a.w;
    o[4] = (bf16)b.x; o[5] = (bf16)b.y; o[6] = (bf16)b.z; o[7] = (bf16)b.w;
    *((bf16x8*)out + i) = o;
  }
}

// --- router: logits, top-2 weights, X->bf16, expert counts (fused) ---
__global__ __launch_bounds__(256) void router_k(const float* __restrict__ X,
                                                const float* __restrict__ R,
                                                bf16* __restrict__ xbf,
                                                int* __restrict__ sel,
                                                float* __restrict__ wts,
                                                int* __restrict__ ctl) {
  int lane = threadIdx.x & 63;
  int t = blockIdx.x * 4 + (threadIdx.x >> 6);
  const float4* x4 = (const float4*)(X + (size_t)t * H_);
  bf16x4* xb4 = (bf16x4*)(xbf + (size_t)t * H_);
  float acc[E_];
#pragma unroll
  for (int e = 0; e < E_; ++e) acc[e] = 0.f;
#pragma unroll
  for (int i = 0; i < H_ / 256; ++i) {
    float4 x = x4[i * 64 + lane];
    bf16x4 xo; xo[0] = (bf16)x.x; xo[1] = (bf16)x.y; xo[2] = (bf16)x.z; xo[3] = (bf16)x.w;
    xb4[i * 64 + lane] = xo;
#pragma unroll
    for (int e = 0; e < E_; ++e) {
      float4 r = ((const float4*)(R + (size_t)e * H_))[i * 64 + lane];
      acc[e] += x.x * r.x + x.y * r.y + x.z * r.z + x.w * r.w;
    }
  }
#pragma unroll
  for (int e = 0; e < E_; ++e)
#pragma unroll
    for (int off = 32; off > 0; off >>= 1) acc[e] += __shfl_xor(acc[e], off);
  if (lane == 0) {
    int e1 = 0; float l1 = acc[0];
#pragma unroll
    for (int e = 1; e < E_; ++e) if (acc[e] > l1) { l1 = acc[e]; e1 = e; }
    int e2 = -1; float l2 = -3.4e38f;
#pragma unroll
    for (int e = 0; e < E_; ++e) if (e != e1 && acc[e] > l2) { l2 = acc[e]; e2 = e; }
    float d = expf(l2 - l1);
    float inv = 1.f / (1.f + d);
    sel[2 * t] = e1; sel[2 * t + 1] = e2;
    wts[2 * t] = inv; wts[2 * t + 1] = d * inv;
    atomicAdd(&ctl[e1], 1);
    atomicAdd(&ctl[e2], 1);
  }
}

// ---------------- routing bookkeeping ----------------
__global__ void prefix_k(int* __restrict__ ctl) {
  if (threadIdx.x == 0) {
    int off = 0;
    for (int e = 0; e < E_; ++e) { ctl[8 + e] = off; ctl[16 + e] = off; off += ctl[e]; }
  }
}
__global__ void scatter_k(const int* __restrict__ sel, const float* __restrict__ wts,
                          int* __restrict__ ctl, int* __restrict__ tok,
                          float* __restrict__ sw) {
  int i = blockIdx.x * blockDim.x + threadIdx.x;
  if (i < NSLOT) {
    int e = sel[i];
    int pos = atomicAdd(&ctl[16 + e], 1);
    tok[pos] = i >> 1;
    sw[pos] = wts[i];
  }
}

// ---- phase fragment loads + MFMA; block-level quadrant (qm,qn) so phase
// reads ONLY A-half qm and B-half qn. 8 waves = 2(wr) x 4(wc) within quad.
#define QLOAD(cur, qm, qn)                                                   \
  _Pragma("unroll") for (int kk = 0; kk < 2; ++kk) {                         \
    _Pragma("unroll") for (int mm = 0; mm < 4; ++mm) {                       \
      int rowA = (qm) * 128 + wr * 64 + mm * 16 + lo;                        \
      af[mm][kk] = *(const bf16x8*)((const char*)lA[cur] + rowA * 128 +      \
                   (((kk * 4 + hi) ^ (rowA & 7)) * 16));                     \
    }                                                                        \
    _Pragma("unroll") for (int nn = 0; nn < 2; ++nn) {                       \
      int rowB = (qn) * 128 + wc * 32 + nn * 16 + lo;                        \
      bfr[nn][kk] = *(const bf16x8*)((const char*)lB[cur] + rowB * 128 +     \
                    (((kk * 4 + hi) ^ (rowB & 7)) * 16));                    \
    }                                                                        \
  }

#define QMFMA(qm, qn)                                                        \
  __builtin_amdgcn_s_setprio(1);                                             \
  _Pragma("unroll") for (int kk = 0; kk < 2; ++kk)                           \
    _Pragma("unroll") for (int mm = 0; mm < 4; ++mm)                         \
      _Pragma("unroll") for (int nn = 0; nn < 2; ++nn)                       \
        acc[(qm) * 4 + mm][(qn) * 2 + nn] =                                  \
            __builtin_amdgcn_mfma_f32_16x16x32_bf16(                         \
                af[mm][kk], bfr[nn][kk], acc[(qm) * 4 + mm][(qn) * 2 + nn],  \
                0, 0, 0);                                                    \
  __builtin_amdgcn_s_setprio(0);

// stage one half-tile (2 gl2lds/thread). h: 0=A0 1=B0 2=A1 3=B1
#define STGA(b, ks, half)                                                    \
  _Pragma("unroll") for (int c = 2 * (half); c < 2 * (half) + 2; ++c)        \
      gl2lds16(asrc[c] + (ks), (char*)lA[b] + loff[c]);
#define STGB(b, ks, half)                                                    \
  _Pragma("unroll") for (int c = 2 * (half); c < 2 * (half) + 2; ++c)        \
      gl2lds16(bsrc[c] + (ks), (char*)lB[b] + loff[c]);

// 8-phase K-loop body (2 barriers/phase, counted vmcnt at p1,p2,p4)
#define KTILE_BODY(cur, nxt, ks)                                             \
  {                                                                          \
    bf16x8 af[4][2], bfr[2][2];                                              \
    QLOAD(cur, 0, 0); STGA(nxt, ks, 0);                                      \
    barr_(); QMFMA(0, 0); vm4_(); barr_();                                   \
    QLOAD(cur, 1, 0); STGB(nxt, ks, 0);                                      \
    barr_(); QMFMA(1, 0); vm4_(); barr_();                                   \
    QLOAD(cur, 0, 1); STGA(nxt, ks, 1);                                      \
    barr_(); QMFMA(0, 1); barr_();                                           \
    QLOAD(cur, 1, 1); STGB(nxt, ks, 1);                                      \
    barr_(); QMFMA(1, 1); vm4_(); barr_();                                   \
  }

// ---------------- GEMM1: act = silu(Xg @ Wg^T) * (Xg @ Wu^T) ----------------
// 256 token-rows x 256 B-rows (gate/up interleaved per 16 rows), BK=64.
__global__ __launch_bounds__(512, 2) void gemm1_k(const bf16* __restrict__ Xb,
                                                  const bf16* __restrict__ Wgu,
                                                  const int* __restrict__ ctl,
                                                  const int* __restrict__ tok,
                                                  bf16* __restrict__ act) {
  constexpr int NMB = T_ / 256;        // 32
  constexpr int NJB = I_ / 128;        // 11
  constexpr int PERX = NMB * NJB;      // 352 blocks per XCD = one expert
  constexpr int NT = H_ / 64;          // 32 K-tiles
  const int L0 = ((int)blockIdx.x & 7) * PERX + ((int)blockIdx.x >> 3);
  const int e = L0 / PERX;
  const int i = L0 % PERX;
  const int j0 = (i / NMB) * 128;      // m innermost: B-tile L2-resident
  const int m0 = (i % NMB) * 256;
  const int cnt = ctl[e];
  if (m0 >= cnt) return;
  const int base = ctl[8 + e];

  __shared__ alignas(16) bf16 lA[2][256 * 64];
  __shared__ alignas(16) bf16 lB[2][256 * 64];

  const int t = threadIdx.x;
  const int lane = t & 63;
  const int wid = t >> 6;
  const int wr = wid >> 2;      // 0..1
  const int wc = wid & 3;       // 0..3
  const int lo = lane & 15, hi = lane >> 4;
  const bf16* wg = Wgu + (size_t)e * (2 * I_) * H_;

  // staging sources; XOR swizzle on the GLOBAL source chunk, LDS dest linear
  const bf16* asrc[4]; const bf16* bsrc[4]; int loff[4];
#pragma unroll
  for (int c = 0; c < 4; ++c) {
    int L = c * 512 + t;
    int row = L >> 3, cc = (L & 7) ^ (row & 7);
    loff[c] = L * 16;
    int r = m0 + row; if (r >= cnt) r = cnt - 1;
    asrc[c] = Xb + (size_t)tok[base + r] * H_ + cc * 8;
    // B rows: 16-row groups alternate gate/up -> lane-local silu epilogue
    int jsub = (row & 15) + ((row >> 5) << 4);
    const bf16* bb = (row & 16) ? wg + (size_t)(I_ + j0 + jsub) * H_
                                : wg + (size_t)(j0 + jsub) * H_;
    bsrc[c] = bb + cc * 8;
  }

  f32x4 zero = {0.f, 0.f, 0.f, 0.f};
  f32x4 acc[8][4];
#pragma unroll
  for (int m = 0; m < 8; ++m)
#pragma unroll
    for (int n = 0; n < 4; ++n) acc[m][n] = zero;

  // prologue: stage tile0 halves in order A0,B0,A1,B1; allow A1,B1 in flight
  STGA(0, 0, 0); STGB(0, 0, 0); STGA(0, 0, 1); STGB(0, 0, 1);
  vm4_();
  barr_();

  for (int kt = 0; kt < NT; ++kt) {
    const int cur = kt & 1, nxt = cur ^ 1;
    const int ks = (kt + 1 < NT) ? (kt + 1) * 64 : 0;  // tail: dummy stage
    KTILE_BODY(cur, nxt, ks);
  }

  // epilogue: acc[mi][qn*2+p]: p=0 gate, p=1 up, same j
#pragma unroll
  for (int mi = 0; mi < 8; ++mi) {
    int trl = (mi >> 2) * 128 + wr * 64 + (mi & 3) * 16 + hi * 4;
#pragma unroll
    for (int r = 0; r < 4; ++r) {
      int row = m0 + trl + r;
      if (row < cnt) {
        bf16* dst = act + (size_t)(base + row) * I_ + j0;
#pragma unroll
        for (int qn = 0; qn < 2; ++qn) {
          float g = acc[mi][qn * 2][r], u = acc[mi][qn * 2 + 1][r];
          dst[qn * 64 + wc * 16 + lo] = (bf16)(g / (1.f + __expf(-g)) * u);
        }
      }
    }
  }
}

// ---------------- GEMM2: out[tok] += w * (act @ Wd^T) ----------------
__global__ __launch_bounds__(512, 2) void gemm2_k(const bf16* __restrict__ act,
                                                  const bf16* __restrict__ Wd,
                                                  const int* __restrict__ ctl,
                                                  const int* __restrict__ tok,
                                                  const float* __restrict__ sw,
                                                  float* __restrict__ out) {
  constexpr int NMB = T_ / 256;        // 32
  constexpr int NJB = H_ / 256;        // 8
  constexpr int PERX = NMB * NJB;      // 256 = one expert per XCD
  constexpr int NT = I_ / 64;          // 22
  const int L0 = ((int)blockIdx.x & 7) * PERX + ((int)blockIdx.x >> 3);
  const int e = L0 / PERX;
  const int i = L0 % PERX;
  const int n0 = (i / NMB) * 256;
  const int m0 = (i % NMB) * 256;
  const int cnt = ctl[e];
  if (m0 >= cnt) return;
  const int base = ctl[8 + e];

  __shared__ alignas(16) bf16 lA[2][256 * 64];
  __shared__ alignas(16) bf16 lB[2][256 * 64];

  const int t = threadIdx.x;
  const int lane = t & 63;
  const int wid = t >> 6;
  const int wr = wid >> 2;
  const int wc = wid & 3;
  const int lo = lane & 15, hi = lane >> 4;
  const bf16* wd = Wd + (size_t)e * H_ * I_;

  const bf16* asrc[4]; const bf16* bsrc[4]; int loff[4];
#pragma unroll
  for (int c = 0; c < 4; ++c) {
    int L = c * 512 + t;
    int row = L >> 3, cc = (L & 7) ^ (row & 7);
    loff[c] = L * 16;
    int r = m0 + row; if (r >= cnt) r = cnt - 1;
    asrc[c] = act + (size_t)(base + r) * I_ + cc * 8;
    bsrc[c] = wd + (size_t)(n0 + row) * I_ + cc * 8;
  }

  f32x4 zero = {0.f, 0.f, 0.f, 0.f};
  f32x4 acc[8][4];
#pragma unroll
  for (int m = 0; m < 8; ++m)
#pragma unroll
    for (int n = 0; n < 4; ++n) acc[m][n] = zero;

  STGA(0, 0, 0); STGB(0, 0, 0); STGA(0, 0, 1); STGB(0, 0, 1);
  vm4_();
  barr_();

  for (int kt = 0; kt < NT; ++kt) {
    const int cur = kt & 1, nxt = cur ^ 1;
    const int ks = (kt + 1 < NT) ? (kt + 1) * 64 : 0;
    KTILE_BODY(cur, nxt, ks);
  }

#pragma unroll
  for (int mi = 0; mi < 8; ++mi) {
    int trl = (mi >> 2) * 128 + wr * 64 + (mi & 3) * 16 + hi * 4;
#pragma unroll
    for (int r = 0; r < 4; ++r) {
      int row = m0 + trl + r;
      if (row < cnt) {
        int token = tok[base + row];
        float w = sw[base + row];
        float* dst = out + (size_t)token * H_ + n0;
#pragma unroll
        for (int ni = 0; ni < 4; ++ni) {
          int col = (ni >> 1) * 128 + wc * 32 + (ni & 1) * 16 + lo;
          atomicAdd(&dst[col], w * acc[mi][ni][r]);
        }
      }
    }
  }
}

// ---------------- host launch ----------------
extern "C" void kernel_launch(void* const* d_in, const int* in_sizes, int n_in,
                              void* d_out, int out_size, void* d_ws, size_t ws_size,
                              hipStream_t stream) {
  const float* X = (const float*)d_in[0];
  const float* R = (const float*)d_in[1];
  const float* Wgu = (const float*)d_in[2];
  const float* Wd = (const float*)d_in[3];
  float* out = (float*)d_out;

  char* ws = (char*)d_ws;
  size_t o = 0;
  auto alloc = [&](size_t sz) { void* p = ws + o; o += (sz + 255) & ~(size_t)255; return p; };
  bf16* wgu_bf = (bf16*)alloc(sizeof(bf16) * (size_t)E_ * 2 * I_ * H_);
  bf16* wd_bf  = (bf16*)alloc(sizeof(bf16) * (size_t)E_ * H_ * I_);
  bf16* xbf    = (bf16*)alloc(sizeof(bf16) * (size_t)T_ * H_);
  bf16* actb   = (bf16*)alloc(sizeof(bf16) * (size_t)NSLOT * I_);
  int* sel     = (int*)alloc(4 * NSLOT);
  float* wts   = (float*)alloc(4 * NSLOT);
  int* tokb    = (int*)alloc(4 * NSLOT);
  float* swb   = (float*)alloc(4 * NSLOT);
  int* ctl     = (int*)alloc(4 * 32);

  hipMemsetAsync(d_out, 0, sizeof(float) * (size_t)out_size, stream);
  hipMemsetAsync(ctl, 0, 4 * 32, stream);

  cvt_k<<<2048, 256, 0, stream>>>(Wgu, wgu_bf, (int)((size_t)E_ * 2 * I_ * H_ / 8));
  cvt_k<<<2048, 256, 0, stream>>>(Wd, wd_bf, (int)((size_t)E_ * H_ * I_ / 8));
  router_k<<<T_ / 4, 256, 0, stream>>>(X, R, xbf, sel, wts, ctl);
  prefix_k<<<1, 64, 0, stream>>>(ctl);
  scatter_k<<<NSLOT / 256, 256, 0, stream>>>(sel, wts, ctl, tokb, swb);
  gemm1_k<<<(T_ / 256) * (I_ / 128) * E_, 512, 0, stream>>>(xbf, wgu_bf, ctl, tokb, actb);
  gemm2_k<<<(T_ / 256) * (H_ / 256) * E_, 512, 0, stream>>>(actb, wd_bf, ctl, tokb, swb, out);
}

// Round 5
// 967.480 us; speedup vs baseline: 1.0533x; 1.0533x over previous
//
#include <hip/hip_runtime.h>
#include <hip/hip_bf16.h>
#include <stdint.h>
#include <math.h>

// SparseMoeBlock: 8 experts, top-2, H=2048, I=1408, T=8192, fp32 in/out.
// R5: dynamic tile table for CU load balance (R4's 8-phase schedule was
// fine; 75% of CUs were idle due to m-index/CU resonance with mostly-empty
// m-blocks). plan_k emits dense (e,j,m) tiles; gemm grids sized to worst
// case, inactive blocks exit. Counted vmcnt(4) at phases 2 & 4 only.

#define E_ 8
#define H_ 2048
#define I_ 1408
#define T_ 8192
#define NSLOT (T_ * 2)
#define MAXNM 71              // max sum of ceil(cnt_e/256)
#define G1 (MAXNM * 11)       // gemm1 worst-case tiles
#define G2 (MAXNM * 8)        // gemm2 worst-case tiles

typedef __bf16 bf16;
typedef bf16 bf16x4 __attribute__((ext_vector_type(4)));
typedef bf16 bf16x8 __attribute__((ext_vector_type(8)));
typedef float f32x4 __attribute__((ext_vector_type(4)));

__device__ inline void gl2lds16(const void* g, void* l) {
  __builtin_amdgcn_global_load_lds(
      (const __attribute__((address_space(1))) unsigned int*)g,
      (__attribute__((address_space(3))) unsigned int*)l, 16, 0, 0);
}
__device__ __forceinline__ void barr_() { __builtin_amdgcn_s_barrier(); }
__device__ __forceinline__ void vm4_() {
  asm volatile("s_waitcnt vmcnt(4)" ::: "memory");
}

// ---------------- fp32 -> bf16 conversion (weights) ----------------
__global__ __launch_bounds__(256) void cvt_k(const float* __restrict__ in,
                                             bf16* __restrict__ out, int n8) {
  int stride = gridDim.x * blockDim.x;
  for (int i = blockIdx.x * blockDim.x + threadIdx.x; i < n8; i += stride) {
    const float4* p = (const float4*)in + (size_t)i * 2;
    float4 a = p[0], b = p[1];
    bf16x8 o;
    o[0] = (bf16)a.x; o[1] = (bf16)a.y; o[2] = (bf16)a.z; o[3] = (bf16)a.w;
    o[4] = (bf16)b.x; o[5] = (bf16)b.y; o[6] = (bf16)b.z; o[7] = (bf16)b.w;
    *((bf16x8*)out + i) = o;
  }
}

// --- router: logits, top-2 weights, X->bf16, expert counts (fused) ---
__global__ __launch_bounds__(256) void router_k(const float* __restrict__ X,
                                                const float* __restrict__ R,
                                                bf16* __restrict__ xbf,
                                                int* __restrict__ sel,
                                                float* __restrict__ wts,
                                                int* __restrict__ ctl) {
  int lane = threadIdx.x & 63;
  int t = blockIdx.x * 4 + (threadIdx.x >> 6);
  const float4* x4 = (const float4*)(X + (size_t)t * H_);
  bf16x4* xb4 = (bf16x4*)(xbf + (size_t)t * H_);
  float acc[E_];
#pragma unroll
  for (int e = 0; e < E_; ++e) acc[e] = 0.f;
#pragma unroll
  for (int i = 0; i < H_ / 256; ++i) {
    float4 x = x4[i * 64 + lane];
    bf16x4 xo; xo[0] = (bf16)x.x; xo[1] = (bf16)x.y; xo[2] = (bf16)x.z; xo[3] = (bf16)x.w;
    xb4[i * 64 + lane] = xo;
#pragma unroll
    for (int e = 0; e < E_; ++e) {
      float4 r = ((const float4*)(R + (size_t)e * H_))[i * 64 + lane];
      acc[e] += x.x * r.x + x.y * r.y + x.z * r.z + x.w * r.w;
    }
  }
#pragma unroll
  for (int e = 0; e < E_; ++e)
#pragma unroll
    for (int off = 32; off > 0; off >>= 1) acc[e] += __shfl_xor(acc[e], off);
  if (lane == 0) {
    int e1 = 0; float l1 = acc[0];
#pragma unroll
    for (int e = 1; e < E_; ++e) if (acc[e] > l1) { l1 = acc[e]; e1 = e; }
    int e2 = -1; float l2 = -3.4e38f;
#pragma unroll
    for (int e = 0; e < E_; ++e) if (e != e1 && acc[e] > l2) { l2 = acc[e]; e2 = e; }
    float d = expf(l2 - l1);
    float inv = 1.f / (1.f + d);
    sel[2 * t] = e1; sel[2 * t + 1] = e2;
    wts[2 * t] = inv; wts[2 * t + 1] = d * inv;
    atomicAdd(&ctl[e1], 1);
    atomicAdd(&ctl[e2], 1);
  }
}

// --- plan: prefix sums + dense tile tables (j-outer, expert, m-inner) ---
// ctl[0..7]=counts, [8..15]=offsets, [16..23]=scatter cursors, [24]=NA1, [25]=NA2
__global__ void plan_k(int* __restrict__ ctl, int* __restrict__ tm1,
                       int* __restrict__ tm2) {
  __shared__ int nm[E_], pref[E_], tot;
  if (threadIdx.x == 0) {
    int off = 0, s = 0;
    for (int e = 0; e < E_; ++e) {
      ctl[8 + e] = off; ctl[16 + e] = off; off += ctl[e];
      nm[e] = (ctl[e] + 255) >> 8; pref[e] = s; s += nm[e];
    }
    tot = s;
    ctl[24] = s * 11;
    ctl[25] = s * 8;
  }
  __syncthreads();
  const int s = tot;
  for (int je = threadIdx.x; je < 11 * E_; je += blockDim.x) {
    int j = je / E_, e = je % E_;
    int b = j * s + pref[e];
    for (int m = 0; m < nm[e]; ++m) tm1[b + m] = (e << 16) | (j << 8) | m;
  }
  for (int je = threadIdx.x; je < 8 * E_; je += blockDim.x) {
    int j = je / E_, e = je % E_;
    int b = j * s + pref[e];
    for (int m = 0; m < nm[e]; ++m) tm2[b + m] = (e << 16) | (j << 8) | m;
  }
}

__global__ void scatter_k(const int* __restrict__ sel, const float* __restrict__ wts,
                          int* __restrict__ ctl, int* __restrict__ tok,
                          float* __restrict__ sw) {
  int i = blockIdx.x * blockDim.x + threadIdx.x;
  if (i < NSLOT) {
    int e = sel[i];
    int pos = atomicAdd(&ctl[16 + e], 1);
    tok[pos] = i >> 1;
    sw[pos] = wts[i];
  }
}

// ---- phase fragment loads + MFMA; block-level quadrant (qm,qn): phase
// reads ONLY A-half qm and B-half qn. 8 waves = 2(wr) x 4(wc) per quad.
#define QLOAD(cur, qm, qn)                                                   \
  _Pragma("unroll") for (int kk = 0; kk < 2; ++kk) {                         \
    _Pragma("unroll") for (int mm = 0; mm < 4; ++mm) {                       \
      int rowA = (qm) * 128 + wr * 64 + mm * 16 + lo;                        \
      af[mm][kk] = *(const bf16x8*)((const char*)lA[cur] + rowA * 128 +      \
                   (((kk * 4 + hi) ^ (rowA & 7)) * 16));                     \
    }                                                                        \
    _Pragma("unroll") for (int nn = 0; nn < 2; ++nn) {                       \
      int rowB = (qn) * 128 + wc * 32 + nn * 16 + lo;                        \
      bfr[nn][kk] = *(const bf16x8*)((const char*)lB[cur] + rowB * 128 +     \
                    (((kk * 4 + hi) ^ (rowB & 7)) * 16));                    \
    }                                                                        \
  }

#define QMFMA(qm, qn)                                                        \
  __builtin_amdgcn_s_setprio(1);                                             \
  _Pragma("unroll") for (int kk = 0; kk < 2; ++kk)                           \
    _Pragma("unroll") for (int mm = 0; mm < 4; ++mm)                         \
      _Pragma("unroll") for (int nn = 0; nn < 2; ++nn)                       \
        acc[(qm) * 4 + mm][(qn) * 2 + nn] =                                  \
            __builtin_amdgcn_mfma_f32_16x16x32_bf16(                         \
                af[mm][kk], bfr[nn][kk], acc[(qm) * 4 + mm][(qn) * 2 + nn],  \
                0, 0, 0);                                                    \
  __builtin_amdgcn_s_setprio(0);

// stage one half-tile (2 gl2lds/thread). half: 0 = rows 0..127, 1 = 128..255
#define STGA(b, ks, half)                                                    \
  _Pragma("unroll") for (int c = 2 * (half); c < 2 * (half) + 2; ++c)        \
      gl2lds16(asrc[c] + (ks), (char*)lA[b] + loff[c]);
#define STGB(b, ks, half)                                                    \
  _Pragma("unroll") for (int c = 2 * (half); c < 2 * (half) + 2; ++c)        \
      gl2lds16(bsrc[c] + (ks), (char*)lB[b] + loff[c]);

// 8-phase K-tile body: counted vmcnt(4) at phases 2 and 4 only.
// Induction (2 loads/half, stage order A0,B0,A1,B1): at tile start
// outstanding = {A1~,B1~}; ph1 +A0' (6); ph2 +B0' (8) vm4 -> retires
// A1~,B1~ (ready for ph3/ph4 reads); ph3 +A1' (6); ph4 +B1' (8) vm4 ->
// retires A0',B0' (ready for next tile ph1/ph2 reads).
#define KTILE_BODY(cur, nxt, ks)                                             \
  {                                                                          \
    bf16x8 af[4][2], bfr[2][2];                                              \
    QLOAD(cur, 0, 0); STGA(nxt, ks, 0);                                      \
    barr_(); QMFMA(0, 0); barr_();                                           \
    QLOAD(cur, 1, 0); STGB(nxt, ks, 0);                                      \
    barr_(); QMFMA(1, 0); vm4_(); barr_();                                   \
    QLOAD(cur, 0, 1); STGA(nxt, ks, 1);                                      \
    barr_(); QMFMA(0, 1); barr_();                                           \
    QLOAD(cur, 1, 1); STGB(nxt, ks, 1);                                      \
    barr_(); QMFMA(1, 1); vm4_(); barr_();                                   \
  }

// ---------------- GEMM1: act = silu(Xg @ Wg^T) * (Xg @ Wu^T) ----------------
// 256 token-rows x 256 B-rows (gate/up interleaved per 16 rows), BK=64.
__global__ __launch_bounds__(512, 2) void gemm1_k(const bf16* __restrict__ Xb,
                                                  const bf16* __restrict__ Wgu,
                                                  const int* __restrict__ ctl,
                                                  const int* __restrict__ tok,
                                                  const int* __restrict__ tmap,
                                                  bf16* __restrict__ act) {
  constexpr int NT = H_ / 64;          // 32 K-tiles
  if ((int)blockIdx.x >= ctl[24]) return;
  const int ent = tmap[blockIdx.x];
  const int e = ent >> 16;
  const int j0 = ((ent >> 8) & 255) * 128;
  const int m0 = (ent & 255) * 256;
  const int cnt = ctl[e];
  const int base = ctl[8 + e];

  __shared__ alignas(16) bf16 lA[2][256 * 64];
  __shared__ alignas(16) bf16 lB[2][256 * 64];

  const int t = threadIdx.x;
  const int lane = t & 63;
  const int wid = t >> 6;
  const int wr = wid >> 2;      // 0..1
  const int wc = wid & 3;       // 0..3
  const int lo = lane & 15, hi = lane >> 4;
  const bf16* wg = Wgu + (size_t)e * (2 * I_) * H_;

  // staging sources; XOR swizzle on the GLOBAL source chunk, LDS dest linear
  const bf16* asrc[4]; const bf16* bsrc[4]; int loff[4];
#pragma unroll
  for (int c = 0; c < 4; ++c) {
    int L = c * 512 + t;
    int row = L >> 3, cc = (L & 7) ^ (row & 7);
    loff[c] = L * 16;
    int r = m0 + row; if (r >= cnt) r = cnt - 1;
    asrc[c] = Xb + (size_t)tok[base + r] * H_ + cc * 8;
    // B rows: 16-row groups alternate gate/up -> lane-local silu epilogue
    int jsub = (row & 15) + ((row >> 5) << 4);
    const bf16* bb = (row & 16) ? wg + (size_t)(I_ + j0 + jsub) * H_
                                : wg + (size_t)(j0 + jsub) * H_;
    bsrc[c] = bb + cc * 8;
  }

  f32x4 zero = {0.f, 0.f, 0.f, 0.f};
  f32x4 acc[8][4];
#pragma unroll
  for (int m = 0; m < 8; ++m)
#pragma unroll
    for (int n = 0; n < 4; ++n) acc[m][n] = zero;

  // prologue: stage tile0 (A0,B0,A1,B1); leave A1,B1 in flight
  STGA(0, 0, 0); STGB(0, 0, 0); STGA(0, 0, 1); STGB(0, 0, 1);
  vm4_();
  barr_();

  for (int kt = 0; kt < NT; ++kt) {
    const int cur = kt & 1, nxt = cur ^ 1;
    const int ks = (kt + 1 < NT) ? (kt + 1) * 64 : 0;  // tail: dummy stage
    KTILE_BODY(cur, nxt, ks);
  }

  // epilogue: acc[mi][qn*2+p]: p=0 gate, p=1 up, same j
#pragma unroll
  for (int mi = 0; mi < 8; ++mi) {
    int trl = (mi >> 2) * 128 + wr * 64 + (mi & 3) * 16 + hi * 4;
#pragma unroll
    for (int r = 0; r < 4; ++r) {
      int row = m0 + trl + r;
      if (row < cnt) {
        bf16* dst = act + (size_t)(base + row) * I_ + j0;
#pragma unroll
        for (int qn = 0; qn < 2; ++qn) {
          float g = acc[mi][qn * 2][r], u = acc[mi][qn * 2 + 1][r];
          dst[qn * 64 + wc * 16 + lo] = (bf16)(g / (1.f + __expf(-g)) * u);
        }
      }
    }
  }
}

// ---------------- GEMM2: out[tok] += w * (act @ Wd^T) ----------------
__global__ __launch_bounds__(512, 2) void gemm2_k(const bf16* __restrict__ act,
                                                  const bf16* __restrict__ Wd,
                                                  const int* __restrict__ ctl,
                                                  const int* __restrict__ tok,
                                                  const float* __restrict__ sw,
                                                  const int* __restrict__ tmap,
                                                  float* __restrict__ out) {
  constexpr int NT = I_ / 64;          // 22 K-tiles
  if ((int)blockIdx.x >= ctl[25]) return;
  const int ent = tmap[blockIdx.x];
  const int e = ent >> 16;
  const int n0 = ((ent >> 8) & 255) * 256;
  const int m0 = (ent & 255) * 256;
  const int cnt = ctl[e];
  const int base = ctl[8 + e];

  __shared__ alignas(16) bf16 lA[2][256 * 64];
  __shared__ alignas(16) bf16 lB[2][256 * 64];

  const int t = threadIdx.x;
  const int lane = t & 63;
  const int wid = t >> 6;
  const int wr = wid >> 2;
  const int wc = wid & 3;
  const int lo = lane & 15, hi = lane >> 4;
  const bf16* wd = Wd + (size_t)e * H_ * I_;

  const bf16* asrc[4]; const bf16* bsrc[4]; int loff[4];
#pragma unroll
  for (int c = 0; c < 4; ++c) {
    int L = c * 512 + t;
    int row = L >> 3, cc = (L & 7) ^ (row & 7);
    loff[c] = L * 16;
    int r = m0 + row; if (r >= cnt) r = cnt - 1;
    asrc[c] = act + (size_t)(base + r) * I_ + cc * 8;
    bsrc[c] = wd + (size_t)(n0 + row) * I_ + cc * 8;
  }

  f32x4 zero = {0.f, 0.f, 0.f, 0.f};
  f32x4 acc[8][4];
#pragma unroll
  for (int m = 0; m < 8; ++m)
#pragma unroll
    for (int n = 0; n < 4; ++n) acc[m][n] = zero;

  STGA(0, 0, 0); STGB(0, 0, 0); STGA(0, 0, 1); STGB(0, 0, 1);
  vm4_();
  barr_();

  for (int kt = 0; kt < NT; ++kt) {
    const int cur = kt & 1, nxt = cur ^ 1;
    const int ks = (kt + 1 < NT) ? (kt + 1) * 64 : 0;
    KTILE_BODY(cur, nxt, ks);
  }

#pragma unroll
  for (int mi = 0; mi < 8; ++mi) {
    int trl = (mi >> 2) * 128 + wr * 64 + (mi & 3) * 16 + hi * 4;
#pragma unroll
    for (int r = 0; r < 4; ++r) {
      int row = m0 + trl + r;
      if (row < cnt) {
        int token = tok[base + row];
        float w = sw[base + row];
        float* dst = out + (size_t)token * H_ + n0;
#pragma unroll
        for (int ni = 0; ni < 4; ++ni) {
          int col = (ni >> 1) * 128 + wc * 32 + (ni & 1) * 16 + lo;
          atomicAdd(&dst[col], w * acc[mi][ni][r]);
        }
      }
    }
  }
}

// ---------------- host launch ----------------
extern "C" void kernel_launch(void* const* d_in, const int* in_sizes, int n_in,
                              void* d_out, int out_size, void* d_ws, size_t ws_size,
                              hipStream_t stream) {
  const float* X = (const float*)d_in[0];
  const float* R = (const float*)d_in[1];
  const float* Wgu = (const float*)d_in[2];
  const float* Wd = (const float*)d_in[3];
  float* out = (float*)d_out;

  char* ws = (char*)d_ws;
  size_t o = 0;
  auto alloc = [&](size_t sz) { void* p = ws + o; o += (sz + 255) & ~(size_t)255; return p; };
  bf16* wgu_bf = (bf16*)alloc(sizeof(bf16) * (size_t)E_ * 2 * I_ * H_);
  bf16* wd_bf  = (bf16*)alloc(sizeof(bf16) * (size_t)E_ * H_ * I_);
  bf16* xbf    = (bf16*)alloc(sizeof(bf16) * (size_t)T_ * H_);
  bf16* actb   = (bf16*)alloc(sizeof(bf16) * (size_t)NSLOT * I_);
  int* sel     = (int*)alloc(4 * NSLOT);
  float* wts   = (float*)alloc(4 * NSLOT);
  int* tokb    = (int*)alloc(4 * NSLOT);
  float* swb   = (float*)alloc(4 * NSLOT);
  int* ctl     = (int*)alloc(4 * 32);
  int* tm1     = (int*)alloc(4 * 1024);
  int* tm2     = (int*)alloc(4 * 1024);

  hipMemsetAsync(d_out, 0, sizeof(float) * (size_t)out_size, stream);
  hipMemsetAsync(ctl, 0, 4 * 32, stream);

  cvt_k<<<2048, 256, 0, stream>>>(Wgu, wgu_bf, (int)((size_t)E_ * 2 * I_ * H_ / 8));
  cvt_k<<<2048, 256, 0, stream>>>(Wd, wd_bf, (int)((size_t)E_ * H_ * I_ / 8));
  router_k<<<T_ / 4, 256, 0, stream>>>(X, R, xbf, sel, wts, ctl);
  plan_k<<<1, 128, 0, stream>>>(ctl, tm1, tm2);
  scatter_k<<<NSLOT / 256, 256, 0, stream>>>(sel, wts, ctl, tokb, swb);
  gemm1_k<<<G1, 512, 0, stream>>>(xbf, wgu_bf, ctl, tokb, tm1, actb);
  gemm2_k<<<G2, 512, 0, stream>>>(actb, wd_bf, ctl, tokb, swb, tm2, out);
}

// Round 6
// 945.869 us; speedup vs baseline: 1.0774x; 1.0228x over previous
//
#include <hip/hip_runtime.h>
#include <hip/hip_bf16.h>
#include <stdint.h>
#include <math.h>

// SparseMoeBlock: 8 experts, top-2, H=2048, I=1408, T=8192, fp32 in/out.
// R6: (a) single-read fragment schedule: B-frags of both halves persist in
// regs; quadrant order (0,0),(0,1),(1,1),(1,0) -> 24 ds_read_b128/wave/Ktile
// (was 48), LDS cycles now == MFMA cycles. (b) uniform vmcnt(4) pipeline,
// one half-tile staged per phase (order A0',B0',B1',A1'), each retires >=2
// phases after issue. (c) XCD-strided tile tables: pair (e,j) -> XCD
// (e+j)&7, entries at idx = xcd + 8*slot -> B-tile lives in one L2.

#define E_ 8
#define H_ 2048
#define I_ 1408
#define T_ 8192
#define NSLOT (T_ * 2)
#define MAXNM 71              // max sum_e ceil(cnt_e/256)
#define G1X 144               // per-XCD gemm1 tile bound
#define G1 (8 * G1X)          // 1152
#define G2 (8 * MAXNM)        // 568

typedef __bf16 bf16;
typedef bf16 bf16x4 __attribute__((ext_vector_type(4)));
typedef bf16 bf16x8 __attribute__((ext_vector_type(8)));
typedef float f32x4 __attribute__((ext_vector_type(4)));

__device__ inline void gl2lds16(const void* g, void* l) {
  __builtin_amdgcn_global_load_lds(
      (const __attribute__((address_space(1))) unsigned int*)g,
      (__attribute__((address_space(3))) unsigned int*)l, 16, 0, 0);
}
__device__ __forceinline__ void barr_() { __builtin_amdgcn_s_barrier(); }
__device__ __forceinline__ void vm4_() {
  asm volatile("s_waitcnt vmcnt(4)" ::: "memory");
}

// ---------------- fp32 -> bf16 conversion (weights) ----------------
__global__ __launch_bounds__(256) void cvt_k(const float* __restrict__ in,
                                             bf16* __restrict__ out, int n8) {
  int stride = gridDim.x * blockDim.x;
  for (int i = blockIdx.x * blockDim.x + threadIdx.x; i < n8; i += stride) {
    const float4* p = (const float4*)in + (size_t)i * 2;
    float4 a = p[0], b = p[1];
    bf16x8 o;
    o[0] = (bf16)a.x; o[1] = (bf16)a.y; o[2] = (bf16)a.z; o[3] = (bf16)a.w;
    o[4] = (bf16)b.x; o[5] = (bf16)b.y; o[6] = (bf16)b.z; o[7] = (bf16)b.w;
    *((bf16x8*)out + i) = o;
  }
}

// --- router: logits, top-2 weights, X->bf16, expert counts (fused) ---
__global__ __launch_bounds__(256) void router_k(const float* __restrict__ X,
                                                const float* __restrict__ R,
                                                bf16* __restrict__ xbf,
                                                int* __restrict__ sel,
                                                float* __restrict__ wts,
                                                int* __restrict__ ctl) {
  int lane = threadIdx.x & 63;
  int t = blockIdx.x * 4 + (threadIdx.x >> 6);
  const float4* x4 = (const float4*)(X + (size_t)t * H_);
  bf16x4* xb4 = (bf16x4*)(xbf + (size_t)t * H_);
  float acc[E_];
#pragma unroll
  for (int e = 0; e < E_; ++e) acc[e] = 0.f;
#pragma unroll
  for (int i = 0; i < H_ / 256; ++i) {
    float4 x = x4[i * 64 + lane];
    bf16x4 xo; xo[0] = (bf16)x.x; xo[1] = (bf16)x.y; xo[2] = (bf16)x.z; xo[3] = (bf16)x.w;
    xb4[i * 64 + lane] = xo;
#pragma unroll
    for (int e = 0; e < E_; ++e) {
      float4 r = ((const float4*)(R + (size_t)e * H_))[i * 64 + lane];
      acc[e] += x.x * r.x + x.y * r.y + x.z * r.z + x.w * r.w;
    }
  }
#pragma unroll
  for (int e = 0; e < E_; ++e)
#pragma unroll
    for (int off = 32; off > 0; off >>= 1) acc[e] += __shfl_xor(acc[e], off);
  if (lane == 0) {
    int e1 = 0; float l1 = acc[0];
#pragma unroll
    for (int e = 1; e < E_; ++e) if (acc[e] > l1) { l1 = acc[e]; e1 = e; }
    int e2 = -1; float l2 = -3.4e38f;
#pragma unroll
    for (int e = 0; e < E_; ++e) if (e != e1 && acc[e] > l2) { l2 = acc[e]; e2 = e; }
    float d = expf(l2 - l1);
    float inv = 1.f / (1.f + d);
    sel[2 * t] = e1; sel[2 * t + 1] = e2;
    wts[2 * t] = inv; wts[2 * t + 1] = d * inv;
    atomicAdd(&ctl[e1], 1);
    atomicAdd(&ctl[e2], 1);
  }
}

// --- plan: prefix sums + XCD-strided tile tables ---
// pair (e,j) -> xcd (e+j)&7; entries at [xcd + 8*slot]; pad entries = -1
// (tables pre-memset to 0xFF host-side). ctl[0..7]=counts, [8..15]=offsets,
// [16..23]=scatter cursors.
__global__ void plan_k(int* __restrict__ ctl, int* __restrict__ tm1,
                       int* __restrict__ tm2) {
  if (threadIdx.x != 0) return;
  int nm[E_];
  int off = 0;
  for (int e = 0; e < E_; ++e) {
    ctl[8 + e] = off; ctl[16 + e] = off; off += ctl[e];
    nm[e] = (ctl[e] + 255) >> 8;
  }
  int cur[8] = {0, 0, 0, 0, 0, 0, 0, 0};
  for (int j = 0; j < 11; ++j)
    for (int e = 0; e < E_; ++e) {
      int x = (e + j) & 7;
      for (int m = 0; m < nm[e]; ++m) {
        tm1[x + 8 * cur[x]] = (e << 16) | (j << 8) | m;
        cur[x]++;
      }
    }
  int cur2[8] = {0, 0, 0, 0, 0, 0, 0, 0};
  for (int n = 0; n < 8; ++n)
    for (int e = 0; e < E_; ++e) {
      int x = (e + n) & 7;
      for (int m = 0; m < nm[e]; ++m) {
        tm2[x + 8 * cur2[x]] = (e << 16) | (n << 8) | m;
        cur2[x]++;
      }
    }
}

__global__ void scatter_k(const int* __restrict__ sel, const float* __restrict__ wts,
                          int* __restrict__ ctl, int* __restrict__ tok,
                          float* __restrict__ sw) {
  int i = blockIdx.x * blockDim.x + threadIdx.x;
  if (i < NSLOT) {
    int e = sel[i];
    int pos = atomicAdd(&ctl[16 + e], 1);
    tok[pos] = i >> 1;
    sw[pos] = wts[i];
  }
}

// ---- fragment loads: each LDS fragment read ONCE per K-tile ----
#define LOADA(cur, qm)                                                       \
  _Pragma("unroll") for (int kk = 0; kk < 2; ++kk)                           \
    _Pragma("unroll") for (int mm = 0; mm < 4; ++mm) {                       \
      int rowA = (qm) * 128 + wr * 64 + mm * 16 + lo;                        \
      af[mm][kk] = *(const bf16x8*)((const char*)lA[cur] + rowA * 128 +      \
                   (((kk * 4 + hi) ^ (rowA & 7)) * 16));                     \
    }

#define LOADB(cur, qn)                                                       \
  _Pragma("unroll") for (int kk = 0; kk < 2; ++kk)                           \
    _Pragma("unroll") for (int nn = 0; nn < 2; ++nn) {                       \
      int rowB = (qn) * 128 + wc * 32 + nn * 16 + lo;                        \
      bfr[qn][nn][kk] = *(const bf16x8*)((const char*)lB[cur] + rowB * 128 + \
                        (((kk * 4 + hi) ^ (rowB & 7)) * 16));                \
    }

#define QMFMA(qm, qn)                                                        \
  __builtin_amdgcn_s_setprio(1);                                             \
  _Pragma("unroll") for (int kk = 0; kk < 2; ++kk)                           \
    _Pragma("unroll") for (int mm = 0; mm < 4; ++mm)                         \
      _Pragma("unroll") for (int nn = 0; nn < 2; ++nn)                       \
        acc[(qm) * 4 + mm][(qn) * 2 + nn] =                                  \
            __builtin_amdgcn_mfma_f32_16x16x32_bf16(                         \
                af[mm][kk], bfr[qn][nn][kk],                                 \
                acc[(qm) * 4 + mm][(qn) * 2 + nn], 0, 0, 0);                 \
  __builtin_amdgcn_s_setprio(0);

// stage one half-tile (2 gl2lds/thread). half: 0 = rows 0..127, 1 = 128..255
#define STGA(b, ks, half)                                                    \
  _Pragma("unroll") for (int c = 2 * (half); c < 2 * (half) + 2; ++c)        \
      gl2lds16(asrc[c] + (ks), (char*)lA[b] + loff[c]);
#define STGB(b, ks, half)                                                    \
  _Pragma("unroll") for (int c = 2 * (half); c < 2 * (half) + 2; ++c)        \
      gl2lds16(bsrc[c] + (ks), (char*)lB[b] + loff[c]);

// 4-phase K-tile. FIFO induction (2 loads/half; stage order A0',B0',B1',A1';
// entering state outstanding = [B1~,A1~]):
// p1: read A0~,B0~; +A0' (6); vm4 -> retire B1~ (4)
// p2: read B1~;     +B0' (6); vm4 -> retire A1~ (4)
// p3: read A1~;     +B1' (6); no vm
// p4:               +A1' (8); vm4 -> retire A0',B0' -> [B1',A1'] = induction
#define KTILE_BODY(cur, nxt, ks)                                             \
  {                                                                          \
    LOADA(cur, 0); LOADB(cur, 0);                                            \
    STGA(nxt, ks, 0);                                                        \
    barr_(); QMFMA(0, 0); vm4_(); barr_();                                   \
    LOADB(cur, 1);                                                           \
    STGB(nxt, ks, 0);                                                        \
    barr_(); QMFMA(0, 1); vm4_(); barr_();                                   \
    LOADA(cur, 1);                                                           \
    STGB(nxt, ks, 1);                                                        \
    barr_(); QMFMA(1, 1); barr_();                                           \
    STGA(nxt, ks, 1);                                                        \
    barr_(); QMFMA(1, 0); vm4_(); barr_();                                   \
  }

// ---------------- GEMM1: act = silu(Xg @ Wg^T) * (Xg @ Wu^T) ----------------
// 256 token-rows x 256 B-rows (gate/up interleaved per 16 rows), BK=64.
__global__ __launch_bounds__(512, 2) void gemm1_k(const bf16* __restrict__ Xb,
                                                  const bf16* __restrict__ Wgu,
                                                  const int* __restrict__ ctl,
                                                  const int* __restrict__ tok,
                                                  const int* __restrict__ tmap,
                                                  bf16* __restrict__ act) {
  constexpr int NT = H_ / 64;          // 32 K-tiles
  const int ent = tmap[blockIdx.x];
  if (ent < 0) return;
  const int e = ent >> 16;
  const int j0 = ((ent >> 8) & 255) * 128;
  const int m0 = (ent & 255) * 256;
  const int cnt = ctl[e];
  const int base = ctl[8 + e];

  __shared__ alignas(16) bf16 lA[2][256 * 64];
  __shared__ alignas(16) bf16 lB[2][256 * 64];

  const int t = threadIdx.x;
  const int lane = t & 63;
  const int wid = t >> 6;
  const int wr = wid >> 2;      // 0..1
  const int wc = wid & 3;       // 0..3
  const int lo = lane & 15, hi = lane >> 4;
  const bf16* wg = Wgu + (size_t)e * (2 * I_) * H_;

  // staging sources; XOR swizzle on the GLOBAL source chunk, LDS dest linear
  const bf16* asrc[4]; const bf16* bsrc[4]; int loff[4];
#pragma unroll
  for (int c = 0; c < 4; ++c) {
    int L = c * 512 + t;
    int row = L >> 3, cc = (L & 7) ^ (row & 7);
    loff[c] = L * 16;
    int r = m0 + row; if (r >= cnt) r = cnt - 1;
    asrc[c] = Xb + (size_t)tok[base + r] * H_ + cc * 8;
    // B rows: 16-row groups alternate gate/up -> lane-local silu epilogue
    int jsub = (row & 15) + ((row >> 5) << 4);
    const bf16* bb = (row & 16) ? wg + (size_t)(I_ + j0 + jsub) * H_
                                : wg + (size_t)(j0 + jsub) * H_;
    bsrc[c] = bb + cc * 8;
  }

  f32x4 zero = {0.f, 0.f, 0.f, 0.f};
  f32x4 acc[8][4];
#pragma unroll
  for (int m = 0; m < 8; ++m)
#pragma unroll
    for (int n = 0; n < 4; ++n) acc[m][n] = zero;

  // prologue: stage tile0 in order A0,B0,B1,A1; vm4 retires A0,B0
  STGA(0, 0, 0); STGB(0, 0, 0); STGB(0, 0, 1); STGA(0, 0, 1);
  vm4_();
  barr_();

  for (int kt = 0; kt < NT; ++kt) {
    const int cur = kt & 1, nxt = cur ^ 1;
    const int ks = (kt + 1 < NT) ? (kt + 1) * 64 : 0;  // tail: dummy stage
    bf16x8 af[4][2], bfr[2][2][2];
    KTILE_BODY(cur, nxt, ks);
  }

  // epilogue: acc[mi][qn*2+p]: p=0 gate, p=1 up, same j
#pragma unroll
  for (int mi = 0; mi < 8; ++mi) {
    int trl = (mi >> 2) * 128 + wr * 64 + (mi & 3) * 16 + hi * 4;
#pragma unroll
    for (int r = 0; r < 4; ++r) {
      int row = m0 + trl + r;
      if (row < cnt) {
        bf16* dst = act + (size_t)(base + row) * I_ + j0;
#pragma unroll
        for (int qn = 0; qn < 2; ++qn) {
          float g = acc[mi][qn * 2][r], u = acc[mi][qn * 2 + 1][r];
          dst[qn * 64 + wc * 16 + lo] = (bf16)(g / (1.f + __expf(-g)) * u);
        }
      }
    }
  }
}

// ---------------- GEMM2: out[tok] += w * (act @ Wd^T) ----------------
__global__ __launch_bounds__(512, 2) void gemm2_k(const bf16* __restrict__ act,
                                                  const bf16* __restrict__ Wd,
                                                  const int* __restrict__ ctl,
                                                  const int* __restrict__ tok,
                                                  const float* __restrict__ sw,
                                                  const int* __restrict__ tmap,
                                                  float* __restrict__ out) {
  constexpr int NT = I_ / 64;          // 22 K-tiles
  const int ent = tmap[blockIdx.x];
  if (ent < 0) return;
  const int e = ent >> 16;
  const int n0 = ((ent >> 8) & 255) * 256;
  const int m0 = (ent & 255) * 256;
  const int cnt = ctl[e];
  const int base = ctl[8 + e];

  __shared__ alignas(16) bf16 lA[2][256 * 64];
  __shared__ alignas(16) bf16 lB[2][256 * 64];

  const int t = threadIdx.x;
  const int lane = t & 63;
  const int wid = t >> 6;
  const int wr = wid >> 2;
  const int wc = wid & 3;
  const int lo = lane & 15, hi = lane >> 4;
  const bf16* wd = Wd + (size_t)e * H_ * I_;

  const bf16* asrc[4]; const bf16* bsrc[4]; int loff[4];
#pragma unroll
  for (int c = 0; c < 4; ++c) {
    int L = c * 512 + t;
    int row = L >> 3, cc = (L & 7) ^ (row & 7);
    loff[c] = L * 16;
    int r = m0 + row; if (r >= cnt) r = cnt - 1;
    asrc[c] = act + (size_t)(base + r) * I_ + cc * 8;
    bsrc[c] = wd + (size_t)(n0 + row) * I_ + cc * 8;
  }

  f32x4 zero = {0.f, 0.f, 0.f, 0.f};
  f32x4 acc[8][4];
#pragma unroll
  for (int m = 0; m < 8; ++m)
#pragma unroll
    for (int n = 0; n < 4; ++n) acc[m][n] = zero;

  STGA(0, 0, 0); STGB(0, 0, 0); STGB(0, 0, 1); STGA(0, 0, 1);
  vm4_();
  barr_();

  for (int kt = 0; kt < NT; ++kt) {
    const int cur = kt & 1, nxt = cur ^ 1;
    const int ks = (kt + 1 < NT) ? (kt + 1) * 64 : 0;
    bf16x8 af[4][2], bfr[2][2][2];
    KTILE_BODY(cur, nxt, ks);
  }

#pragma unroll
  for (int mi = 0; mi < 8; ++mi) {
    int trl = (mi >> 2) * 128 + wr * 64 + (mi & 3) * 16 + hi * 4;
#pragma unroll
    for (int r = 0; r < 4; ++r) {
      int row = m0 + trl + r;
      if (row < cnt) {
        int token = tok[base + row];
        float w = sw[base + row];
        float* dst = out + (size_t)token * H_ + n0;
#pragma unroll
        for (int ni = 0; ni < 4; ++ni) {
          int col = (ni >> 1) * 128 + wc * 32 + (ni & 1) * 16 + lo;
          atomicAdd(&dst[col], w * acc[mi][ni][r]);
        }
      }
    }
  }
}

// ---------------- host launch ----------------
extern "C" void kernel_launch(void* const* d_in, const int* in_sizes, int n_in,
                              void* d_out, int out_size, void* d_ws, size_t ws_size,
                              hipStream_t stream) {
  const float* X = (const float*)d_in[0];
  const float* R = (const float*)d_in[1];
  const float* Wgu = (const float*)d_in[2];
  const float* Wd = (const float*)d_in[3];
  float* out = (float*)d_out;

  char* ws = (char*)d_ws;
  size_t o = 0;
  auto alloc = [&](size_t sz) { void* p = ws + o; o += (sz + 255) & ~(size_t)255; return p; };
  bf16* wgu_bf = (bf16*)alloc(sizeof(bf16) * (size_t)E_ * 2 * I_ * H_);
  bf16* wd_bf  = (bf16*)alloc(sizeof(bf16) * (size_t)E_ * H_ * I_);
  bf16* xbf    = (bf16*)alloc(sizeof(bf16) * (size_t)T_ * H_);
  bf16* actb   = (bf16*)alloc(sizeof(bf16) * (size_t)NSLOT * I_);
  int* sel     = (int*)alloc(4 * NSLOT);
  float* wts   = (float*)alloc(4 * NSLOT);
  int* tokb    = (int*)alloc(4 * NSLOT);
  float* swb   = (float*)alloc(4 * NSLOT);
  int* ctl     = (int*)alloc(4 * 32);
  int* tm1     = (int*)alloc(4 * G1);
  int* tm2     = (int*)alloc(4 * G2);

  hipMemsetAsync(d_out, 0, sizeof(float) * (size_t)out_size, stream);
  hipMemsetAsync(ctl, 0, 4 * 32, stream);
  hipMemsetAsync(tm1, 0xFF, 4 * G1, stream);
  hipMemsetAsync(tm2, 0xFF, 4 * G2, stream);

  cvt_k<<<2048, 256, 0, stream>>>(Wgu, wgu_bf, (int)((size_t)E_ * 2 * I_ * H_ / 8));
  cvt_k<<<2048, 256, 0, stream>>>(Wd, wd_bf, (int)((size_t)E_ * H_ * I_ / 8));
  router_k<<<T_ / 4, 256, 0, stream>>>(X, R, xbf, sel, wts, ctl);
  plan_k<<<1, 64, 0, stream>>>(ctl, tm1, tm2);
  scatter_k<<<NSLOT / 256, 256, 0, stream>>>(sel, wts, ctl, tokb, swb);
  gemm1_k<<<G1, 512, 0, stream>>>(xbf, wgu_bf, ctl, tokb, tm1, actb);
  gemm2_k<<<G2, 512, 0, stream>>>(actb, wd_bf, ctl, tokb, swb, tm2, out);
}

// Round 7
// 881.358 us; speedup vs baseline: 1.1562x; 1.0732x over previous
//
#include <hip/hip_runtime.h>
#include <hip/hip_bf16.h>
#include <stdint.h>
#include <math.h>

// SparseMoeBlock: 8 experts, top-2, H=2048, I=1408, T=8192, fp32 in/out.
// R7: gemm2 atomics removed -> per-slot bf16 y (weight folded) + combine_k
// (out[t] = y[inv[2t]] + y[inv[2t+1]]). y aliases dead wgu_bf. gemm1
// unchanged from R6 (control for gather-vs-structure diagnosis).

#define E_ 8
#define H_ 2048
#define I_ 1408
#define T_ 8192
#define NSLOT (T_ * 2)
#define MAXNM 71              // max sum_e ceil(cnt_e/256)
#define G1X 144               // per-XCD gemm1 tile bound
#define G1 (8 * G1X)          // 1152
#define G2 (8 * MAXNM)        // 568

typedef __bf16 bf16;
typedef bf16 bf16x4 __attribute__((ext_vector_type(4)));
typedef bf16 bf16x8 __attribute__((ext_vector_type(8)));
typedef float f32x4 __attribute__((ext_vector_type(4)));

__device__ inline void gl2lds16(const void* g, void* l) {
  __builtin_amdgcn_global_load_lds(
      (const __attribute__((address_space(1))) unsigned int*)g,
      (__attribute__((address_space(3))) unsigned int*)l, 16, 0, 0);
}
__device__ __forceinline__ void barr_() { __builtin_amdgcn_s_barrier(); }
__device__ __forceinline__ void vm4_() {
  asm volatile("s_waitcnt vmcnt(4)" ::: "memory");
}

// ---------------- fp32 -> bf16 conversion (weights) ----------------
__global__ __launch_bounds__(256) void cvt_k(const float* __restrict__ in,
                                             bf16* __restrict__ out, int n8) {
  int stride = gridDim.x * blockDim.x;
  for (int i = blockIdx.x * blockDim.x + threadIdx.x; i < n8; i += stride) {
    const float4* p = (const float4*)in + (size_t)i * 2;
    float4 a = p[0], b = p[1];
    bf16x8 o;
    o[0] = (bf16)a.x; o[1] = (bf16)a.y; o[2] = (bf16)a.z; o[3] = (bf16)a.w;
    o[4] = (bf16)b.x; o[5] = (bf16)b.y; o[6] = (bf16)b.z; o[7] = (bf16)b.w;
    *((bf16x8*)out + i) = o;
  }
}

// --- router: logits, top-2 weights, X->bf16, expert counts (fused) ---
__global__ __launch_bounds__(256) void router_k(const float* __restrict__ X,
                                                const float* __restrict__ R,
                                                bf16* __restrict__ xbf,
                                                int* __restrict__ sel,
                                                float* __restrict__ wts,
                                                int* __restrict__ ctl) {
  int lane = threadIdx.x & 63;
  int t = blockIdx.x * 4 + (threadIdx.x >> 6);
  const float4* x4 = (const float4*)(X + (size_t)t * H_);
  bf16x4* xb4 = (bf16x4*)(xbf + (size_t)t * H_);
  float acc[E_];
#pragma unroll
  for (int e = 0; e < E_; ++e) acc[e] = 0.f;
#pragma unroll
  for (int i = 0; i < H_ / 256; ++i) {
    float4 x = x4[i * 64 + lane];
    bf16x4 xo; xo[0] = (bf16)x.x; xo[1] = (bf16)x.y; xo[2] = (bf16)x.z; xo[3] = (bf16)x.w;
    xb4[i * 64 + lane] = xo;
#pragma unroll
    for (int e = 0; e < E_; ++e) {
      float4 r = ((const float4*)(R + (size_t)e * H_))[i * 64 + lane];
      acc[e] += x.x * r.x + x.y * r.y + x.z * r.z + x.w * r.w;
    }
  }
#pragma unroll
  for (int e = 0; e < E_; ++e)
#pragma unroll
    for (int off = 32; off > 0; off >>= 1) acc[e] += __shfl_xor(acc[e], off);
  if (lane == 0) {
    int e1 = 0; float l1 = acc[0];
#pragma unroll
    for (int e = 1; e < E_; ++e) if (acc[e] > l1) { l1 = acc[e]; e1 = e; }
    int e2 = -1; float l2 = -3.4e38f;
#pragma unroll
    for (int e = 0; e < E_; ++e) if (e != e1 && acc[e] > l2) { l2 = acc[e]; e2 = e; }
    float d = expf(l2 - l1);
    float inv = 1.f / (1.f + d);
    sel[2 * t] = e1; sel[2 * t + 1] = e2;
    wts[2 * t] = inv; wts[2 * t + 1] = d * inv;
    atomicAdd(&ctl[e1], 1);
    atomicAdd(&ctl[e2], 1);
  }
}

// --- plan: prefix sums + XCD-strided tile tables ---
// pair (e,j) -> xcd (e+j)&7; entries at [xcd + 8*slot]; pad entries = -1
__global__ void plan_k(int* __restrict__ ctl, int* __restrict__ tm1,
                       int* __restrict__ tm2) {
  if (threadIdx.x != 0) return;
  int nm[E_];
  int off = 0;
  for (int e = 0; e < E_; ++e) {
    ctl[8 + e] = off; ctl[16 + e] = off; off += ctl[e];
    nm[e] = (ctl[e] + 255) >> 8;
  }
  int cur[8] = {0, 0, 0, 0, 0, 0, 0, 0};
  for (int j = 0; j < 11; ++j)
    for (int e = 0; e < E_; ++e) {
      int x = (e + j) & 7;
      for (int m = 0; m < nm[e]; ++m) {
        tm1[x + 8 * cur[x]] = (e << 16) | (j << 8) | m;
        cur[x]++;
      }
    }
  int cur2[8] = {0, 0, 0, 0, 0, 0, 0, 0};
  for (int n = 0; n < 8; ++n)
    for (int e = 0; e < E_; ++e) {
      int x = (e + n) & 7;
      for (int m = 0; m < nm[e]; ++m) {
        tm2[x + 8 * cur2[x]] = (e << 16) | (n << 8) | m;
        cur2[x]++;
      }
    }
}

// scatter: compacted slot lists + inverse map (token,k) -> slot position
__global__ void scatter_k(const int* __restrict__ sel, const float* __restrict__ wts,
                          int* __restrict__ ctl, int* __restrict__ tok,
                          float* __restrict__ sw, int* __restrict__ inv) {
  int i = blockIdx.x * blockDim.x + threadIdx.x;
  if (i < NSLOT) {
    int e = sel[i];
    int pos = atomicAdd(&ctl[16 + e], 1);
    tok[pos] = i >> 1;
    sw[pos] = wts[i];
    inv[i] = pos;
  }
}

// ---- fragment loads: each LDS fragment read ONCE per K-tile ----
#define LOADA(cur, qm)                                                       \
  _Pragma("unroll") for (int kk = 0; kk < 2; ++kk)                           \
    _Pragma("unroll") for (int mm = 0; mm < 4; ++mm) {                       \
      int rowA = (qm) * 128 + wr * 64 + mm * 16 + lo;                        \
      af[mm][kk] = *(const bf16x8*)((const char*)lA[cur] + rowA * 128 +      \
                   (((kk * 4 + hi) ^ (rowA & 7)) * 16));                     \
    }

#define LOADB(cur, qn)                                                       \
  _Pragma("unroll") for (int kk = 0; kk < 2; ++kk)                           \
    _Pragma("unroll") for (int nn = 0; nn < 2; ++nn) {                       \
      int rowB = (qn) * 128 + wc * 32 + nn * 16 + lo;                        \
      bfr[qn][nn][kk] = *(const bf16x8*)((const char*)lB[cur] + rowB * 128 + \
                        (((kk * 4 + hi) ^ (rowB & 7)) * 16));                \
    }

#define QMFMA(qm, qn)                                                        \
  __builtin_amdgcn_s_setprio(1);                                             \
  _Pragma("unroll") for (int kk = 0; kk < 2; ++kk)                           \
    _Pragma("unroll") for (int mm = 0; mm < 4; ++mm)                         \
      _Pragma("unroll") for (int nn = 0; nn < 2; ++nn)                       \
        acc[(qm) * 4 + mm][(qn) * 2 + nn] =                                  \
            __builtin_amdgcn_mfma_f32_16x16x32_bf16(                         \
                af[mm][kk], bfr[qn][nn][kk],                                 \
                acc[(qm) * 4 + mm][(qn) * 2 + nn], 0, 0, 0);                 \
  __builtin_amdgcn_s_setprio(0);

// stage one half-tile (2 gl2lds/thread). half: 0 = rows 0..127, 1 = 128..255
#define STGA(b, ks, half)                                                    \
  _Pragma("unroll") for (int c = 2 * (half); c < 2 * (half) + 2; ++c)        \
      gl2lds16(asrc[c] + (ks), (char*)lA[b] + loff[c]);
#define STGB(b, ks, half)                                                    \
  _Pragma("unroll") for (int c = 2 * (half); c < 2 * (half) + 2; ++c)        \
      gl2lds16(bsrc[c] + (ks), (char*)lB[b] + loff[c]);

// 4-phase K-tile. FIFO induction (2 loads/half; stage order A0',B0',B1',A1';
// entering state outstanding = [B1~,A1~]):
// p1: read A0~,B0~; +A0' (6); vm4 -> retire B1~ (4)
// p2: read B1~;     +B0' (6); vm4 -> retire A1~ (4)
// p3: read A1~;     +B1' (6); no vm
// p4:               +A1' (8); vm4 -> retire A0',B0' -> [B1',A1'] = induction
#define KTILE_BODY(cur, nxt, ks)                                             \
  {                                                                          \
    LOADA(cur, 0); LOADB(cur, 0);                                            \
    STGA(nxt, ks, 0);                                                        \
    barr_(); QMFMA(0, 0); vm4_(); barr_();                                   \
    LOADB(cur, 1);                                                           \
    STGB(nxt, ks, 0);                                                        \
    barr_(); QMFMA(0, 1); vm4_(); barr_();                                   \
    LOADA(cur, 1);                                                           \
    STGB(nxt, ks, 1);                                                        \
    barr_(); QMFMA(1, 1); barr_();                                           \
    STGA(nxt, ks, 1);                                                        \
    barr_(); QMFMA(1, 0); vm4_(); barr_();                                   \
  }

// ---------------- GEMM1: act = silu(Xg @ Wg^T) * (Xg @ Wu^T) ----------------
// 256 token-rows x 256 B-rows (gate/up interleaved per 16 rows), BK=64.
__global__ __launch_bounds__(512, 2) void gemm1_k(const bf16* __restrict__ Xb,
                                                  const bf16* __restrict__ Wgu,
                                                  const int* __restrict__ ctl,
                                                  const int* __restrict__ tok,
                                                  const int* __restrict__ tmap,
                                                  bf16* __restrict__ act) {
  constexpr int NT = H_ / 64;          // 32 K-tiles
  const int ent = tmap[blockIdx.x];
  if (ent < 0) return;
  const int e = ent >> 16;
  const int j0 = ((ent >> 8) & 255) * 128;
  const int m0 = (ent & 255) * 256;
  const int cnt = ctl[e];
  const int base = ctl[8 + e];

  __shared__ alignas(16) bf16 lA[2][256 * 64];
  __shared__ alignas(16) bf16 lB[2][256 * 64];

  const int t = threadIdx.x;
  const int lane = t & 63;
  const int wid = t >> 6;
  const int wr = wid >> 2;      // 0..1
  const int wc = wid & 3;       // 0..3
  const int lo = lane & 15, hi = lane >> 4;
  const bf16* wg = Wgu + (size_t)e * (2 * I_) * H_;

  // staging sources; XOR swizzle on the GLOBAL source chunk, LDS dest linear
  const bf16* asrc[4]; const bf16* bsrc[4]; int loff[4];
#pragma unroll
  for (int c = 0; c < 4; ++c) {
    int L = c * 512 + t;
    int row = L >> 3, cc = (L & 7) ^ (row & 7);
    loff[c] = L * 16;
    int r = m0 + row; if (r >= cnt) r = cnt - 1;
    asrc[c] = Xb + (size_t)tok[base + r] * H_ + cc * 8;
    // B rows: 16-row groups alternate gate/up -> lane-local silu epilogue
    int jsub = (row & 15) + ((row >> 5) << 4);
    const bf16* bb = (row & 16) ? wg + (size_t)(I_ + j0 + jsub) * H_
                                : wg + (size_t)(j0 + jsub) * H_;
    bsrc[c] = bb + cc * 8;
  }

  f32x4 zero = {0.f, 0.f, 0.f, 0.f};
  f32x4 acc[8][4];
#pragma unroll
  for (int m = 0; m < 8; ++m)
#pragma unroll
    for (int n = 0; n < 4; ++n) acc[m][n] = zero;

  // prologue: stage tile0 in order A0,B0,B1,A1; vm4 retires A0,B0
  STGA(0, 0, 0); STGB(0, 0, 0); STGB(0, 0, 1); STGA(0, 0, 1);
  vm4_();
  barr_();

  for (int kt = 0; kt < NT; ++kt) {
    const int cur = kt & 1, nxt = cur ^ 1;
    const int ks = (kt + 1 < NT) ? (kt + 1) * 64 : 0;  // tail: dummy stage
    bf16x8 af[4][2], bfr[2][2][2];
    KTILE_BODY(cur, nxt, ks);
  }

  // epilogue: acc[mi][qn*2+p]: p=0 gate, p=1 up, same j
#pragma unroll
  for (int mi = 0; mi < 8; ++mi) {
    int trl = (mi >> 2) * 128 + wr * 64 + (mi & 3) * 16 + hi * 4;
#pragma unroll
    for (int r = 0; r < 4; ++r) {
      int row = m0 + trl + r;
      if (row < cnt) {
        bf16* dst = act + (size_t)(base + row) * I_ + j0;
#pragma unroll
        for (int qn = 0; qn < 2; ++qn) {
          float g = acc[mi][qn * 2][r], u = acc[mi][qn * 2 + 1][r];
          dst[qn * 64 + wc * 16 + lo] = (bf16)(g / (1.f + __expf(-g)) * u);
        }
      }
    }
  }
}

// ---------------- GEMM2: y[slot] = w * (act @ Wd^T), bf16, no atomics ------
__global__ __launch_bounds__(512, 2) void gemm2_k(const bf16* __restrict__ act,
                                                  const bf16* __restrict__ Wd,
                                                  const int* __restrict__ ctl,
                                                  const float* __restrict__ sw,
                                                  const int* __restrict__ tmap,
                                                  bf16* __restrict__ y) {
  constexpr int NT = I_ / 64;          // 22 K-tiles
  const int ent = tmap[blockIdx.x];
  if (ent < 0) return;
  const int e = ent >> 16;
  const int n0 = ((ent >> 8) & 255) * 256;
  const int m0 = (ent & 255) * 256;
  const int cnt = ctl[e];
  const int base = ctl[8 + e];

  __shared__ alignas(16) bf16 lA[2][256 * 64];
  __shared__ alignas(16) bf16 lB[2][256 * 64];

  const int t = threadIdx.x;
  const int lane = t & 63;
  const int wid = t >> 6;
  const int wr = wid >> 2;
  const int wc = wid & 3;
  const int lo = lane & 15, hi = lane >> 4;
  const bf16* wd = Wd + (size_t)e * H_ * I_;

  const bf16* asrc[4]; const bf16* bsrc[4]; int loff[4];
#pragma unroll
  for (int c = 0; c < 4; ++c) {
    int L = c * 512 + t;
    int row = L >> 3, cc = (L & 7) ^ (row & 7);
    loff[c] = L * 16;
    int r = m0 + row; if (r >= cnt) r = cnt - 1;
    asrc[c] = act + (size_t)(base + r) * I_ + cc * 8;
    bsrc[c] = wd + (size_t)(n0 + row) * I_ + cc * 8;
  }

  f32x4 zero = {0.f, 0.f, 0.f, 0.f};
  f32x4 acc[8][4];
#pragma unroll
  for (int m = 0; m < 8; ++m)
#pragma unroll
    for (int n = 0; n < 4; ++n) acc[m][n] = zero;

  STGA(0, 0, 0); STGB(0, 0, 0); STGB(0, 0, 1); STGA(0, 0, 1);
  vm4_();
  barr_();

  for (int kt = 0; kt < NT; ++kt) {
    const int cur = kt & 1, nxt = cur ^ 1;
    const int ks = (kt + 1 < NT) ? (kt + 1) * 64 : 0;
    bf16x8 af[4][2], bfr[2][2][2];
    KTILE_BODY(cur, nxt, ks);
  }

#pragma unroll
  for (int mi = 0; mi < 8; ++mi) {
    int trl = (mi >> 2) * 128 + wr * 64 + (mi & 3) * 16 + hi * 4;
#pragma unroll
    for (int r = 0; r < 4; ++r) {
      int row = m0 + trl + r;
      if (row < cnt) {
        float w = sw[base + row];
        bf16* dst = y + (size_t)(base + row) * H_ + n0;
#pragma unroll
        for (int ni = 0; ni < 4; ++ni) {
          int col = (ni >> 1) * 128 + wc * 32 + (ni & 1) * 16 + lo;
          dst[col] = (bf16)(w * acc[mi][ni][r]);
        }
      }
    }
  }
}

// ---------------- combine: out[t] = y[inv[2t]] + y[inv[2t+1]] ----------------
__global__ __launch_bounds__(256) void combine_k(const bf16* __restrict__ y,
                                                 const int* __restrict__ inv,
                                                 float* __restrict__ out) {
  int idx = blockIdx.x * 256 + threadIdx.x;  // one bf16x8 chunk per thread
  int t = idx >> 8;                          // H_/8 = 256 chunks per token
  int c = idx & 255;
  int i1 = inv[2 * t], i2 = inv[2 * t + 1];
  bf16x8 a = *((const bf16x8*)(y + (size_t)i1 * H_) + c);
  bf16x8 b = *((const bf16x8*)(y + (size_t)i2 * H_) + c);
  float* op = out + (size_t)t * H_ + c * 8;
#pragma unroll
  for (int k = 0; k < 8; ++k) op[k] = (float)a[k] + (float)b[k];
}

// ---------------- host launch ----------------
extern "C" void kernel_launch(void* const* d_in, const int* in_sizes, int n_in,
                              void* d_out, int out_size, void* d_ws, size_t ws_size,
                              hipStream_t stream) {
  const float* X = (const float*)d_in[0];
  const float* R = (const float*)d_in[1];
  const float* Wgu = (const float*)d_in[2];
  const float* Wd = (const float*)d_in[3];
  float* out = (float*)d_out;

  char* ws = (char*)d_ws;
  size_t o = 0;
  auto alloc = [&](size_t sz) { void* p = ws + o; o += (sz + 255) & ~(size_t)255; return p; };
  bf16* wgu_bf = (bf16*)alloc(sizeof(bf16) * (size_t)E_ * 2 * I_ * H_);
  bf16* wd_bf  = (bf16*)alloc(sizeof(bf16) * (size_t)E_ * H_ * I_);
  bf16* xbf    = (bf16*)alloc(sizeof(bf16) * (size_t)T_ * H_);
  bf16* actb   = (bf16*)alloc(sizeof(bf16) * (size_t)NSLOT * I_);
  int* sel     = (int*)alloc(4 * NSLOT);
  float* wts   = (float*)alloc(4 * NSLOT);
  int* tokb    = (int*)alloc(4 * NSLOT);
  float* swb   = (float*)alloc(4 * NSLOT);
  int* invb    = (int*)alloc(4 * NSLOT);
  int* ctl     = (int*)alloc(4 * 32);
  int* tm1     = (int*)alloc(4 * G1);
  int* tm2     = (int*)alloc(4 * G2);
  // y (NSLOT x H bf16, 67 MB) aliases wgu_bf (92 MB), dead after gemm1
  bf16* yb = wgu_bf;

  hipMemsetAsync(ctl, 0, 4 * 32, stream);
  hipMemsetAsync(tm1, 0xFF, 4 * G1, stream);
  hipMemsetAsync(tm2, 0xFF, 4 * G2, stream);

  cvt_k<<<2048, 256, 0, stream>>>(Wgu, wgu_bf, (int)((size_t)E_ * 2 * I_ * H_ / 8));
  cvt_k<<<2048, 256, 0, stream>>>(Wd, wd_bf, (int)((size_t)E_ * H_ * I_ / 8));
  router_k<<<T_ / 4, 256, 0, stream>>>(X, R, xbf, sel, wts, ctl);
  plan_k<<<1, 64, 0, stream>>>(ctl, tm1, tm2);
  scatter_k<<<NSLOT / 256, 256, 0, stream>>>(sel, wts, ctl, tokb, swb, invb);
  gemm1_k<<<G1, 512, 0, stream>>>(xbf, wgu_bf, ctl, tokb, tm1, actb);
  gemm2_k<<<G2, 512, 0, stream>>>(actb, wd_bf, ctl, swb, tm2, yb);
  combine_k<<<T_ * H_ / 2048, 256, 0, stream>>>(yb, invb, out);
}

// Round 9
// 602.286 us; speedup vs baseline: 1.6920x; 1.4634x over previous
//
#include <hip/hip_runtime.h>
#include <hip/hip_bf16.h>
#include <stdint.h>
#include <math.h>

// SparseMoeBlock: 8 experts, top-2, H=2048, I=1408, T=8192, fp32 in/out.
// R9 = R8 with corrected tile-table capacities (R8 overflow: per-XCD slot
// demand with 128-row tiles is 3*135=405 (gemm1) / 2*135=270 (gemm2); R8
// provisioned 384/256 -> ~112 gemm2 tiles never ran -> poison in y).
// GEMMs: 2-phase dbuf 64KB, 2 blocks/CU, dense XCD-affine tile tables.
// Routing bookkeeping atomic-free (LDS histogram + ballot ranks).

#define E_ 8
#define H_ 2048
#define I_ 1408
#define T_ 8192
#define NSLOT (T_ * 2)
#define NBLK 64               // count/scatter blocks (NSLOT/256)
#define G1S 408               // per-XCD gemm1 slots (>= 3*135)
#define G2S 272               // per-XCD gemm2 slots (>= 2*135)
#define G1 (8 * G1S)          // 3264
#define G2 (8 * G2S)          // 2176

typedef __bf16 bf16;
typedef bf16 bf16x4 __attribute__((ext_vector_type(4)));
typedef bf16 bf16x8 __attribute__((ext_vector_type(8)));
typedef float f32x4 __attribute__((ext_vector_type(4)));

__device__ inline void gl2lds16(const void* g, void* l) {
  __builtin_amdgcn_global_load_lds(
      (const __attribute__((address_space(1))) unsigned int*)g,
      (__attribute__((address_space(3))) unsigned int*)l, 16, 0, 0);
}

// ------------- fused fp32 -> bf16 conversion for both weight tensors -------
__global__ __launch_bounds__(256) void cvtw_k(const float* __restrict__ a, int n8a,
                                              const float* __restrict__ b, int n8b,
                                              bf16* __restrict__ oa,
                                              bf16* __restrict__ ob) {
  int stride = gridDim.x * blockDim.x;
  int ntot = n8a + n8b;
  for (int i = blockIdx.x * blockDim.x + threadIdx.x; i < ntot; i += stride) {
    const float* src; bf16* dst; int k;
    if (i < n8a) { src = a; dst = oa; k = i; }
    else         { src = b; dst = ob; k = i - n8a; }
    const float4* p = (const float4*)src + (size_t)k * 2;
    float4 x = p[0], y = p[1];
    bf16x8 o;
    o[0] = (bf16)x.x; o[1] = (bf16)x.y; o[2] = (bf16)x.z; o[3] = (bf16)x.w;
    o[4] = (bf16)y.x; o[5] = (bf16)y.y; o[6] = (bf16)y.z; o[7] = (bf16)y.w;
    *((bf16x8*)dst + k) = o;
  }
}

// ------------- router: logits, top-2 weights, X -> bf16 (no atomics) -------
__global__ __launch_bounds__(256) void router_k(const float* __restrict__ X,
                                                const float* __restrict__ R,
                                                bf16* __restrict__ xbf,
                                                int* __restrict__ sel,
                                                float* __restrict__ wts) {
  int lane = threadIdx.x & 63;
  int t = blockIdx.x * 4 + (threadIdx.x >> 6);
  const float4* x4 = (const float4*)(X + (size_t)t * H_);
  bf16x4* xb4 = (bf16x4*)(xbf + (size_t)t * H_);
  float acc[E_];
#pragma unroll
  for (int e = 0; e < E_; ++e) acc[e] = 0.f;
#pragma unroll
  for (int i = 0; i < H_ / 256; ++i) {
    float4 x = x4[i * 64 + lane];
    bf16x4 xo; xo[0] = (bf16)x.x; xo[1] = (bf16)x.y; xo[2] = (bf16)x.z; xo[3] = (bf16)x.w;
    xb4[i * 64 + lane] = xo;
#pragma unroll
    for (int e = 0; e < E_; ++e) {
      float4 r = ((const float4*)(R + (size_t)e * H_))[i * 64 + lane];
      acc[e] += x.x * r.x + x.y * r.y + x.z * r.z + x.w * r.w;
    }
  }
#pragma unroll
  for (int e = 0; e < E_; ++e)
#pragma unroll
    for (int off = 32; off > 0; off >>= 1) acc[e] += __shfl_xor(acc[e], off);
  if (lane == 0) {
    int e1 = 0; float l1 = acc[0];
#pragma unroll
    for (int e = 1; e < E_; ++e) if (acc[e] > l1) { l1 = acc[e]; e1 = e; }
    int e2 = -1; float l2 = -3.4e38f;
#pragma unroll
    for (int e = 0; e < E_; ++e) if (e != e1 && acc[e] > l2) { l2 = acc[e]; e2 = e; }
    float d = expf(l2 - l1);
    float inv = 1.f / (1.f + d);
    sel[2 * t] = e1; sel[2 * t + 1] = e2;
    wts[2 * t] = inv; wts[2 * t + 1] = d * inv;
  }
}

// ------------- count: per-block expert histogram (LDS atomics only) -------
__global__ __launch_bounds__(256) void count_k(const int* __restrict__ sel,
                                               int* __restrict__ blockHist) {
  __shared__ int h[E_];
  int t = threadIdx.x;
  if (t < E_) h[t] = 0;
  __syncthreads();
  atomicAdd(&h[sel[blockIdx.x * 256 + t]], 1);
  __syncthreads();
  if (t < E_) blockHist[blockIdx.x * E_ + t] = h[t];
}

// ------------- plan: counts, offsets, scatter bases, tile tables -------
// ctl[0..7]=counts, ctl[8..15]=offsets. Tables: pair (e,j)->xcd (e+j)&7,
// entries at [xcd + 8*slot] -> all m-blocks of a pair on one XCD.
__global__ __launch_bounds__(256) void plan_k(const int* __restrict__ blockHist,
                                              int* __restrict__ ctl,
                                              int* __restrict__ blockBase,
                                              int* __restrict__ tm1,
                                              int* __restrict__ tm2) {
  __shared__ int cnts[E_], offs[E_], nm8[E_];
  __shared__ int ps1[22 * E_], ps2[16 * E_];
  int t = threadIdx.x;
  if (t < E_) {
    int c = 0;
    for (int b = 0; b < NBLK; ++b) c += blockHist[b * E_ + t];
    cnts[t] = c; ctl[t] = c;
  }
  __syncthreads();
  if (t == 0) {
    int off = 0;
    for (int e = 0; e < E_; ++e) {
      offs[e] = off; ctl[8 + e] = off; off += cnts[e];
      nm8[e] = (cnts[e] + 127) >> 7;
    }
    int cur1[8] = {0, 0, 0, 0, 0, 0, 0, 0};
    for (int pid = 0; pid < 22 * E_; ++pid) {
      int j = pid >> 3, e = pid & 7, x = (e + j) & 7;
      ps1[pid] = cur1[x]; cur1[x] += nm8[e];
    }
    int cur2[8] = {0, 0, 0, 0, 0, 0, 0, 0};
    for (int pid = 0; pid < 16 * E_; ++pid) {
      int n = pid >> 3, e = pid & 7, x = (e + n) & 7;
      ps2[pid] = cur2[x]; cur2[x] += nm8[e];
    }
  }
  __syncthreads();
  if (t < E_) {  // per-block scatter bases: column-wise exclusive scan
    int run = offs[t];
    for (int b = 0; b < NBLK; ++b) {
      blockBase[b * E_ + t] = run;
      run += blockHist[b * E_ + t];
    }
  }
  for (int pid = t; pid < 22 * E_; pid += 256) {
    int j = pid >> 3, e = pid & 7, x = (e + j) & 7;
    for (int m = 0; m < nm8[e]; ++m)
      tm1[x + 8 * (ps1[pid] + m)] = (e << 16) | (j << 8) | m;
  }
  for (int pid = t; pid < 16 * E_; pid += 256) {
    int n = pid >> 3, e = pid & 7, x = (e + n) & 7;
    for (int m = 0; m < nm8[e]; ++m)
      tm2[x + 8 * (ps2[pid] + m)] = (e << 16) | (n << 8) | m;
  }
}

// ------------- scatter: deterministic, atomic-free (ballot ranks) -------
__global__ __launch_bounds__(256) void scatter_k(const int* __restrict__ sel,
                                                 const float* __restrict__ wts,
                                                 const int* __restrict__ blockBase,
                                                 int* __restrict__ tok,
                                                 float* __restrict__ sw,
                                                 int* __restrict__ inv) {
  __shared__ int wcnt[4][E_];
  int t = threadIdx.x;
  int lane = t & 63, w = t >> 6;
  int i = blockIdx.x * 256 + t;
  int e = sel[i];
  unsigned long long below = (lane == 63) ? ~0ull >> 1 : (1ull << lane) - 1;
  int myrank = 0;
#pragma unroll
  for (int e0 = 0; e0 < E_; ++e0) {
    unsigned long long m = __ballot(e == e0);
    if (e == e0) myrank = __popcll(m & below);
    if (lane == 0) wcnt[w][e0] = __popcll(m);
  }
  __syncthreads();
  int pos = blockBase[blockIdx.x * E_ + e] + myrank;
#pragma unroll
  for (int w2 = 0; w2 < 3; ++w2)
    if (w2 < w) pos += wcnt[w2][e];
  tok[pos] = i >> 1;
  sw[pos] = wts[i];
  inv[i] = pos;
}

// ---------------- GEMM1: act = silu(Xg @ Wg^T) * (Xg @ Wu^T) ----------------
// 128 token-rows x 64 j-cols (gate+up panels), BK=64, 4 waves, 2-phase dbuf,
// 64 KB LDS -> 2 blocks/CU.
__global__ __launch_bounds__(256, 2) void gemm1_k(const bf16* __restrict__ Xb,
                                                  const bf16* __restrict__ Wgu,
                                                  const int* __restrict__ ctl,
                                                  const int* __restrict__ tok,
                                                  const int* __restrict__ tmap,
                                                  bf16* __restrict__ act) {
  const int ent = tmap[blockIdx.x];
  if (ent < 0) return;
  const int e = ent >> 16;
  const int j0 = ((ent >> 8) & 255) * 64;
  const int m0 = (ent & 255) * 128;
  const int cnt = ctl[e];
  const int base = ctl[8 + e];

  __shared__ alignas(16) bf16 lA[2][128 * 64];
  __shared__ alignas(16) bf16 lBg[2][64 * 64];
  __shared__ alignas(16) bf16 lBu[2][64 * 64];

  const int t = threadIdx.x;
  const int lane = t & 63;
  const int wr = (t >> 7) & 1;
  const int wc = (t >> 6) & 1;
  const int lo = lane & 15, hi = lane >> 4;
  const bf16* wg = Wgu + (size_t)e * (2 * I_) * H_;

  // staging; XOR swizzle on the GLOBAL source chunk, LDS dest linear
  const bf16* asrc[4]; int aoff[4];
#pragma unroll
  for (int c = 0; c < 4; ++c) {
    int L = c * 256 + t;
    int row = L >> 3, cc = (L & 7) ^ (row & 7);
    int r = m0 + row; if (r >= cnt) r = cnt - 1;
    asrc[c] = Xb + (size_t)tok[base + r] * H_ + cc * 8;
    aoff[c] = L * 16;
  }
  const bf16* gsrc[2]; const bf16* usrc[2]; int boff[2];
#pragma unroll
  for (int c = 0; c < 2; ++c) {
    int L = c * 256 + t;
    int row = L >> 3, cc = (L & 7) ^ (row & 7);
    gsrc[c] = wg + (size_t)(j0 + row) * H_ + cc * 8;
    usrc[c] = wg + (size_t)(I_ + j0 + row) * H_ + cc * 8;
    boff[c] = L * 16;
  }

#define STG1(b, k)                                                \
  {                                                               \
    _Pragma("unroll")                                             \
    for (int c = 0; c < 4; ++c)                                   \
      gl2lds16(asrc[c] + (k), (char*)lA[b] + aoff[c]);            \
    _Pragma("unroll")                                             \
    for (int c = 0; c < 2; ++c) {                                 \
      gl2lds16(gsrc[c] + (k), (char*)lBg[b] + boff[c]);           \
      gl2lds16(usrc[c] + (k), (char*)lBu[b] + boff[c]);           \
    }                                                             \
  }

  f32x4 zero = {0.f, 0.f, 0.f, 0.f};
  f32x4 ag[4][2], au[4][2];
#pragma unroll
  for (int m = 0; m < 4; ++m)
#pragma unroll
    for (int n = 0; n < 2; ++n) { ag[m][n] = zero; au[m][n] = zero; }

  STG1(0, 0);
  __syncthreads();

  for (int k0 = 0; k0 < H_; k0 += 128) {
#pragma unroll
    for (int p = 0; p < 2; ++p) {
      const int kc = k0 + p * 64;
      if (kc + 64 < H_) STG1(p ^ 1, kc + 64);   // prefetch next K-tile
#pragma unroll
      for (int kk = 0; kk < 2; ++kk) {
        const int chunk = kk * 4 + hi;
        bf16x8 af[4], bg[2], bu[2];
#pragma unroll
        for (int m = 0; m < 4; ++m) {
          int row = wr * 64 + m * 16 + lo;
          af[m] = *(const bf16x8*)((const char*)lA[p] + row * 128 + ((chunk ^ (row & 7)) * 16));
        }
#pragma unroll
        for (int n = 0; n < 2; ++n) {
          int row = wc * 32 + n * 16 + lo;
          int sw2 = (chunk ^ (row & 7)) * 16;
          bg[n] = *(const bf16x8*)((const char*)lBg[p] + row * 128 + sw2);
          bu[n] = *(const bf16x8*)((const char*)lBu[p] + row * 128 + sw2);
        }
#pragma unroll
        for (int m = 0; m < 4; ++m)
#pragma unroll
          for (int n = 0; n < 2; ++n) {
            ag[m][n] = __builtin_amdgcn_mfma_f32_16x16x32_bf16(af[m], bg[n], ag[m][n], 0, 0, 0);
            au[m][n] = __builtin_amdgcn_mfma_f32_16x16x32_bf16(af[m], bu[n], au[m][n], 0, 0, 0);
          }
      }
      __syncthreads();
    }
  }
#undef STG1

#pragma unroll
  for (int m = 0; m < 4; ++m)
#pragma unroll
    for (int r = 0; r < 4; ++r) {
      int row = m0 + wr * 64 + m * 16 + hi * 4 + r;
      if (row < cnt) {
        bf16* dst = act + (size_t)(base + row) * I_ + j0 + wc * 32 + lo;
#pragma unroll
        for (int n = 0; n < 2; ++n) {
          float g = ag[m][n][r], u = au[m][n][r];
          dst[n * 16] = (bf16)(g / (1.f + __expf(-g)) * u);
        }
      }
    }
}

// ---------------- GEMM2: y[slot] = w * (act @ Wd^T), bf16, no atomics ------
// 128 slot-rows x 128 H-cols, BK=64, 4 waves, 2-phase dbuf, 64 KB LDS.
__global__ __launch_bounds__(256, 2) void gemm2_k(const bf16* __restrict__ act,
                                                  const bf16* __restrict__ Wd,
                                                  const int* __restrict__ ctl,
                                                  const float* __restrict__ sw,
                                                  const int* __restrict__ tmap,
                                                  bf16* __restrict__ y) {
  const int ent = tmap[blockIdx.x];
  if (ent < 0) return;
  const int e = ent >> 16;
  const int n0 = ((ent >> 8) & 255) * 128;
  const int m0 = (ent & 255) * 128;
  const int cnt = ctl[e];
  const int base = ctl[8 + e];

  __shared__ alignas(16) bf16 lA[2][128 * 64];
  __shared__ alignas(16) bf16 lB[2][128 * 64];

  const int t = threadIdx.x;
  const int lane = t & 63;
  const int wr = (t >> 7) & 1;
  const int wc = (t >> 6) & 1;
  const int lo = lane & 15, hi = lane >> 4;
  const bf16* wd = Wd + (size_t)e * H_ * I_;

  const bf16* asrc[4]; int aoff[4];
#pragma unroll
  for (int c = 0; c < 4; ++c) {
    int L = c * 256 + t;
    int row = L >> 3, cc = (L & 7) ^ (row & 7);
    int r = m0 + row; if (r >= cnt) r = cnt - 1;
    asrc[c] = act + (size_t)(base + r) * I_ + cc * 8;
    aoff[c] = L * 16;
  }
  const bf16* bsrc[4]; int boff[4];
#pragma unroll
  for (int c = 0; c < 4; ++c) {
    int L = c * 256 + t;
    int row = L >> 3, cc = (L & 7) ^ (row & 7);
    bsrc[c] = wd + (size_t)(n0 + row) * I_ + cc * 8;
    boff[c] = L * 16;
  }

#define STG2(b, k)                                                \
  {                                                               \
    _Pragma("unroll")                                             \
    for (int c = 0; c < 4; ++c)                                   \
      gl2lds16(asrc[c] + (k), (char*)lA[b] + aoff[c]);            \
    _Pragma("unroll")                                             \
    for (int c = 0; c < 4; ++c)                                   \
      gl2lds16(bsrc[c] + (k), (char*)lB[b] + boff[c]);            \
  }

  f32x4 zero = {0.f, 0.f, 0.f, 0.f};
  f32x4 acc[4][4];
#pragma unroll
  for (int m = 0; m < 4; ++m)
#pragma unroll
    for (int n = 0; n < 4; ++n) acc[m][n] = zero;

  STG2(0, 0);
  __syncthreads();

  for (int k0 = 0; k0 < I_; k0 += 128) {
#pragma unroll
    for (int p = 0; p < 2; ++p) {
      const int kc = k0 + p * 64;
      if (kc + 64 < I_) STG2(p ^ 1, kc + 64);
#pragma unroll
      for (int kk = 0; kk < 2; ++kk) {
        const int chunk = kk * 4 + hi;
        bf16x8 af[4], bb[4];
#pragma unroll
        for (int m = 0; m < 4; ++m) {
          int row = wr * 64 + m * 16 + lo;
          af[m] = *(const bf16x8*)((const char*)lA[p] + row * 128 + ((chunk ^ (row & 7)) * 16));
        }
#pragma unroll
        for (int n = 0; n < 4; ++n) {
          int row = wc * 64 + n * 16 + lo;
          bb[n] = *(const bf16x8*)((const char*)lB[p] + row * 128 + ((chunk ^ (row & 7)) * 16));
        }
#pragma unroll
        for (int m = 0; m < 4; ++m)
#pragma unroll
          for (int n = 0; n < 4; ++n)
            acc[m][n] = __builtin_amdgcn_mfma_f32_16x16x32_bf16(af[m], bb[n], acc[m][n], 0, 0, 0);
      }
      __syncthreads();
    }
  }
#undef STG2

#pragma unroll
  for (int m = 0; m < 4; ++m)
#pragma unroll
    for (int r = 0; r < 4; ++r) {
      int row = m0 + wr * 64 + m * 16 + hi * 4 + r;
      if (row < cnt) {
        float w = sw[base + row];
        bf16* dst = y + (size_t)(base + row) * H_ + n0 + wc * 64 + lo;
#pragma unroll
        for (int n = 0; n < 4; ++n) dst[n * 16] = (bf16)(w * acc[m][n][r]);
      }
    }
}

// ---------------- combine: out[t] = y[inv[2t]] + y[inv[2t+1]] ----------------
__global__ __launch_bounds__(256) void combine_k(const bf16* __restrict__ y,
                                                 const int* __restrict__ inv,
                                                 float* __restrict__ out) {
  int idx = blockIdx.x * 256 + threadIdx.x;  // one bf16x8 chunk per thread
  int t = idx >> 8;                          // H_/8 = 256 chunks per token
  int c = idx & 255;
  int i1 = inv[2 * t], i2 = inv[2 * t + 1];
  bf16x8 a = *((const bf16x8*)(y + (size_t)i1 * H_) + c);
  bf16x8 b = *((const bf16x8*)(y + (size_t)i2 * H_) + c);
  float* op = out + (size_t)t * H_ + c * 8;
#pragma unroll
  for (int k = 0; k < 8; ++k) op[k] = (float)a[k] + (float)b[k];
}

// ---------------- host launch ----------------
extern "C" void kernel_launch(void* const* d_in, const int* in_sizes, int n_in,
                              void* d_out, int out_size, void* d_ws, size_t ws_size,
                              hipStream_t stream) {
  const float* X = (const float*)d_in[0];
  const float* R = (const float*)d_in[1];
  const float* Wgu = (const float*)d_in[2];
  const float* Wd = (const float*)d_in[3];
  float* out = (float*)d_out;

  char* ws = (char*)d_ws;
  size_t o = 0;
  auto alloc = [&](size_t sz) { void* p = ws + o; o += (sz + 255) & ~(size_t)255; return p; };
  bf16* wgu_bf = (bf16*)alloc(sizeof(bf16) * (size_t)E_ * 2 * I_ * H_);
  bf16* wd_bf  = (bf16*)alloc(sizeof(bf16) * (size_t)E_ * H_ * I_);
  bf16* xbf    = (bf16*)alloc(sizeof(bf16) * (size_t)T_ * H_);
  bf16* actb   = (bf16*)alloc(sizeof(bf16) * (size_t)NSLOT * I_);
  int* sel     = (int*)alloc(4 * NSLOT);
  float* wts   = (float*)alloc(4 * NSLOT);
  int* tokb    = (int*)alloc(4 * NSLOT);
  float* swb   = (float*)alloc(4 * NSLOT);
  int* invb    = (int*)alloc(4 * NSLOT);
  int* ctl     = (int*)alloc(4 * 32);
  int* bh      = (int*)alloc(4 * NBLK * E_);
  int* bb      = (int*)alloc(4 * NBLK * E_);
  int* tm1     = (int*)alloc(4 * G1);
  int* tm2     = (int*)alloc(4 * G2);
  // y (NSLOT x H bf16, 67 MB) aliases wgu_bf (92 MB), dead after gemm1
  bf16* yb = wgu_bf;

  hipMemsetAsync(tm1, 0xFF, 4 * G1, stream);
  hipMemsetAsync(tm2, 0xFF, 4 * G2, stream);

  cvtw_k<<<2048, 256, 0, stream>>>(Wgu, (int)((size_t)E_ * 2 * I_ * H_ / 8),
                                   Wd, (int)((size_t)E_ * H_ * I_ / 8),
                                   wgu_bf, wd_bf);
  router_k<<<T_ / 4, 256, 0, stream>>>(X, R, xbf, sel, wts);
  count_k<<<NBLK, 256, 0, stream>>>(sel, bh);
  plan_k<<<1, 256, 0, stream>>>(bh, ctl, bb, tm1, tm2);
  scatter_k<<<NBLK, 256, 0, stream>>>(sel, wts, bb, tokb, swb, invb);
  gemm1_k<<<G1, 256, 0, stream>>>(xbf, wgu_bf, ctl, tokb, tm1, actb);
  gemm2_k<<<G2, 256, 0, stream>>>(actb, wd_bf, ctl, swb, tm2, yb);
  combine_k<<<T_ * H_ / 2048, 256, 0, stream>>>(yb, invb, out);
}